// Round 1
// baseline (835.280 us; speedup 1.0000x reference)
//
#include <hip/hip_runtime.h>
#include <math.h>

// ---------------------------------------------------------------------------
// HPFNetCovPool: 1x1 conv (GEMM K=2048) -> covpool -> Newton-Schulz sqrtm
// (5 iters, batched 256^3 GEMMs) -> triu-vec -> linear heads.
// Round 1: correct fp32 baseline. GEMM core is generic (templated epilogue +
// optional B-transpose) so it can be swapped for split-bf16 MFMA later.
// ---------------------------------------------------------------------------

#define BM 128
#define BN 64
#define BK 16

enum { EPI_NONE = 0, EPI_BIAS = 1, EPI_COV = 2, EPI_RNORM = 3, EPI_SQRTNORM = 4 };

// C[b] (M=256 x N=256, ldc=256) = A[b] (M x K, lda) @ B[b] (K x N, ldb)
// TRANSB: B is stored transposed (ldb = row stride of B^T), i.e. C = A @ Bt^T.
template <bool TRANSB, int EPI>
__global__ __launch_bounds__(256) void gemm_kernel(
    const float* __restrict__ A, const float* __restrict__ B,
    float* __restrict__ C, const float* __restrict__ aux,
    int K, int lda, int ldb,
    long long strideA, long long strideB, long long strideC)
{
    const int b = blockIdx.z;
    const float* Ab = A + (size_t)b * strideA;
    const float* Bb = B + (size_t)b * strideB;
    float* Cb = C + (size_t)b * strideC;

    __shared__ float As[BK][BM + 4];  // +4 keeps rows 16B-aligned for b128
    __shared__ float Bs[BK][BN + 4];

    const int tid = threadIdx.x;
    const int tx = tid & 15;   // -> j (4 cols)
    const int ty = tid >> 4;   // -> i (8 rows)
    const int ib = blockIdx.y * BM;
    const int jb = blockIdx.x * BN;

    float acc[8][4];
#pragma unroll
    for (int r = 0; r < 8; ++r)
#pragma unroll
        for (int c = 0; c < 4; ++c) acc[r][c] = 0.f;

    const int aq = tid & 3;    // k-quad for A staging
    const int ar = tid >> 2;   // row for A staging (0..63, +64)

    for (int kb = 0; kb < K; kb += BK) {
        // Stage A transposed: As[k][i] = Ab[(ib+i)*lda + kb+k]
#pragma unroll
        for (int h = 0; h < 2; ++h) {
            const int i = ar + h * 64;
            const float4 av = *reinterpret_cast<const float4*>(
                &Ab[(size_t)(ib + i) * lda + kb + 4 * aq]);
            As[4 * aq + 0][i] = av.x;
            As[4 * aq + 1][i] = av.y;
            As[4 * aq + 2][i] = av.z;
            As[4 * aq + 3][i] = av.w;
        }
        if (!TRANSB) {
            // Bs[k][j] = Bb[(kb+k)*ldb + jb+j]
            const int k = tid >> 4, j4 = (tid & 15) * 4;
            const float4 bv = *reinterpret_cast<const float4*>(
                &Bb[(size_t)(kb + k) * ldb + jb + j4]);
            *reinterpret_cast<float4*>(&Bs[k][j4]) = bv;
        } else {
            // Bs[k][j] = Bt[(jb+j)*ldb + kb+k]
            const int q = tid & 3, j = tid >> 2;
            const float4 bv = *reinterpret_cast<const float4*>(
                &Bb[(size_t)(jb + j) * ldb + kb + 4 * q]);
            Bs[4 * q + 0][j] = bv.x;
            Bs[4 * q + 1][j] = bv.y;
            Bs[4 * q + 2][j] = bv.z;
            Bs[4 * q + 3][j] = bv.w;
        }
        __syncthreads();

#pragma unroll
        for (int kk = 0; kk < BK; ++kk) {
            const float4 a0 = *reinterpret_cast<const float4*>(&As[kk][ty * 8]);
            const float4 a1 = *reinterpret_cast<const float4*>(&As[kk][ty * 8 + 4]);
            const float4 bv = *reinterpret_cast<const float4*>(&Bs[kk][tx * 4]);
            const float a[8] = {a0.x, a0.y, a0.z, a0.w, a1.x, a1.y, a1.z, a1.w};
            const float bb2[4] = {bv.x, bv.y, bv.z, bv.w};
#pragma unroll
            for (int r = 0; r < 8; ++r)
#pragma unroll
                for (int c = 0; c < 4; ++c)
                    acc[r][c] = fmaf(a[r], bb2[c], acc[r][c]);
        }
        __syncthreads();
    }

    // Epilogue
    const int i0 = ib + ty * 8;
    const int j0 = jb + tx * 4;
    float scale = 1.0f;
    if constexpr (EPI == EPI_RNORM)    scale = 1.0f / aux[blockIdx.z];
    if constexpr (EPI == EPI_SQRTNORM) scale = sqrtf(aux[blockIdx.z]);
    const float* mub = nullptr;
    if constexpr (EPI == EPI_COV) mub = aux + (size_t)blockIdx.z * 256;

#pragma unroll
    for (int r = 0; r < 8; ++r) {
        const int i = i0 + r;
        float4 v = make_float4(acc[r][0], acc[r][1], acc[r][2], acc[r][3]);
        if constexpr (EPI == EPI_BIAS) {
            const float bi = aux[i];
            v.x += bi; v.y += bi; v.z += bi; v.w += bi;
        } else if constexpr (EPI == EPI_COV) {
            const float mi = mub[i];
            v.x = v.x * (1.f / 256.f) - mi * mub[j0 + 0];
            v.y = v.y * (1.f / 256.f) - mi * mub[j0 + 1];
            v.z = v.z * (1.f / 256.f) - mi * mub[j0 + 2];
            v.w = v.w * (1.f / 256.f) - mi * mub[j0 + 3];
        } else {
            v.x *= scale; v.y *= scale; v.z *= scale; v.w *= scale;
        }
        *reinterpret_cast<float4*>(&Cb[(size_t)i * 256 + j0]) = v;
    }
}

// Row means: mu[b*256+o] = mean_m X[b][o][m]. grid = 64*256 blocks of 64.
__global__ __launch_bounds__(64) void mean_kernel(const float* __restrict__ X,
                                                  float* __restrict__ mu)
{
    const int row = blockIdx.x;
    const int lane = threadIdx.x;
    const float4 v = reinterpret_cast<const float4*>(X + (size_t)row * 256)[lane];
    float s = v.x + v.y + v.z + v.w;
#pragma unroll
    for (int off = 32; off > 0; off >>= 1) s += __shfl_down(s, off);
    if (lane == 0) mu[row] = s * (1.0f / 256.0f);
}

// norm[b] = trace(A[b])
__global__ __launch_bounds__(256) void trace_kernel(const float* __restrict__ A,
                                                    float* __restrict__ norm)
{
    const int b = blockIdx.x;
    const int t = threadIdx.x;
    __shared__ float red[256];
    red[t] = A[(size_t)b * 65536 + (size_t)t * 257];
    __syncthreads();
    for (int off = 128; off > 0; off >>= 1) {
        if (t < off) red[t] += red[t + off];
        __syncthreads();
    }
    if (t == 0) norm[b] = red[0];
}

// ZY = 0.5*(3I - T*scale), scale = 1/norm[b] if NORMALIZE else 1. In-place OK.
template <bool NORMALIZE>
__global__ __launch_bounds__(256) void zy_kernel(const float* __restrict__ T,
                                                 float* __restrict__ ZY,
                                                 const float* __restrict__ norm)
{
    const size_t e = ((size_t)blockIdx.x * 256 + threadIdx.x) * 4;
    const int b = (int)(e >> 16);
    const int t = (int)(e & 65535);
    const int i = t >> 8;
    const int j = t & 255;
    float scale = 1.0f;
    if constexpr (NORMALIZE) scale = 1.0f / norm[b];
    float4 v = *reinterpret_cast<const float4*>(T + e);
    v.x = 0.5f * ((i == j + 0 ? 3.f : 0.f) - v.x * scale);
    v.y = 0.5f * ((i == j + 1 ? 3.f : 0.f) - v.y * scale);
    v.z = 0.5f * ((i == j + 2 ? 3.f : 0.f) - v.z * scale);
    v.w = 0.5f * ((i == j + 3 ? 3.f : 0.f) - v.w * scale);
    *reinterpret_cast<float4*>(ZY + e) = v;
}

// Heads: per batch b, triu-vec dot with 4 type rows + 1 flag row.
__global__ __launch_bounds__(256) void head_kernel(
    const float* __restrict__ Smat, const float* __restrict__ w_type,
    const float* __restrict__ b_type, const float* __restrict__ w_flag,
    const float* __restrict__ b_flag, float* __restrict__ out)
{
    const int b = blockIdx.x;
    const int tid = threadIdx.x;
    const float* Sb = Smat + (size_t)b * 65536;
    float acc[5] = {0.f, 0.f, 0.f, 0.f, 0.f};
    int off = 0;
    for (int r = 0; r < 256; ++r) {
        const int L = 256 - r;
        const float* srow = Sb + r * 256 + r;
        for (int idx = tid; idx < L; idx += 256) {
            const float sv = srow[idx];
            const int f = off + idx;
            acc[0] += sv * w_type[f];
            acc[1] += sv * w_type[32896 + f];
            acc[2] += sv * w_type[2 * 32896 + f];
            acc[3] += sv * w_type[3 * 32896 + f];
            acc[4] += sv * w_flag[f];
        }
        off += L;
    }
    __shared__ float red[256];
    for (int v = 0; v < 5; ++v) {
        red[tid] = acc[v];
        __syncthreads();
        for (int o2 = 128; o2 > 0; o2 >>= 1) {
            if (tid < o2) red[tid] += red[tid + o2];
            __syncthreads();
        }
        if (tid == 0) {
            if (v < 4) out[b * 4 + v] = red[0] + b_type[v];
            else       out[256 + b]  = red[0] + b_flag[0];
        }
        __syncthreads();
    }
}

extern "C" void kernel_launch(void* const* d_in, const int* in_sizes, int n_in,
                              void* d_out, int out_size, void* d_ws, size_t ws_size,
                              hipStream_t stream)
{
    const float* features = (const float*)d_in[0];  // [64,2048,16,16]
    const float* w_bn     = (const float*)d_in[1];  // [256,2048]
    const float* b_bn     = (const float*)d_in[2];  // [256]
    const float* w_type   = (const float*)d_in[3];  // [4,32896]
    const float* b_type   = (const float*)d_in[4];  // [4]
    const float* w_flag   = (const float*)d_in[5];  // [1,32896]
    const float* b_flag   = (const float*)d_in[6];  // [1]
    float* out = (float*)d_out;                     // 320 = 64*4 + 64

    const size_t S = 64ull * 256 * 256;  // one batched 256x256 fp32 tensor
    float* W0 = (float*)d_ws;
    float* W1 = W0 + S;
    float* W2 = W1 + S;
    float* W3 = W2 + S;
    float* mu   = W3 + S;        // 64*256
    float* norm = mu + 64 * 256; // 64

    const dim3 block(256);
    const dim3 gg(256 / BN, 256 / BM, 64);  // (4,2,64)
    const long long SB = 65536;

    // 1. Conv 1x1: X(W0)[b] = w_bn @ F[b] + b_bn.  K=2048.
    gemm_kernel<false, EPI_BIAS><<<gg, block, 0, stream>>>(
        w_bn, features, W0, b_bn, 2048, 2048, 256, 0, 2048LL * 256, SB);
    // 2. Row means of X.
    mean_kernel<<<dim3(64 * 256), dim3(64), 0, stream>>>(W0, mu);
    // 3. Cov: A(W1) = X@X^T/256 - mu mu^T.
    gemm_kernel<true, EPI_COV><<<gg, block, 0, stream>>>(
        W0, W0, W1, mu, 256, 256, 256, SB, SB, SB);
    // 4. norm[b] = trace(A[b]).
    trace_kernel<<<dim3(64), block, 0, stream>>>(W1, norm);
    // 5. ZY0(W2) = 0.5*(3I - A/norm).
    zy_kernel<true><<<dim3(4096), block, 0, stream>>>(W1, W2, norm);
    // 6. Y0(W3) = (A @ ZY0)/norm.   Z0 aliases ZY0 (W2).
    gemm_kernel<false, EPI_RNORM><<<gg, block, 0, stream>>>(
        W1, W2, W3, norm, 256, 256, 256, SB, SB, SB);

    float* Y = W3;
    float* Z = W2;
    float* F0 = W0;  // per-iter temp (T / ZY)
    float* F1 = W1;  // per-iter new-Y target
    for (int it = 0; it < 3; ++it) {
        // T(F0) = Z@Y ; ZY = 0.5*(3I - T) in-place.
        gemm_kernel<false, EPI_NONE><<<gg, block, 0, stream>>>(
            Z, Y, F0, nullptr, 256, 256, 256, SB, SB, SB);
        zy_kernel<false><<<dim3(4096), block, 0, stream>>>(F0, F0, nullptr);
        // Ynew(F1) = Y @ ZY ; Znew(old Y buffer) = ZY @ Z.
        gemm_kernel<false, EPI_NONE><<<gg, block, 0, stream>>>(
            Y, F0, F1, nullptr, 256, 256, 256, SB, SB, SB);
        gemm_kernel<false, EPI_NONE><<<gg, block, 0, stream>>>(
            F0, Z, Y, nullptr, 256, 256, 256, SB, SB, SB);
        float* newY = F1;
        float* newZ = Y;
        float* oldZ = Z;
        Y = newY; Z = newZ; F1 = oldZ;
    }

    // Final: T(W0) = Z@Y ; E = 0.5*(3I - T) ; S(F1) = (Y @ E) * sqrt(norm).
    gemm_kernel<false, EPI_NONE><<<gg, block, 0, stream>>>(
        Z, Y, F0, nullptr, 256, 256, 256, SB, SB, SB);
    zy_kernel<false><<<dim3(4096), block, 0, stream>>>(F0, F0, nullptr);
    gemm_kernel<false, EPI_SQRTNORM><<<gg, block, 0, stream>>>(
        Y, F0, F1, norm, 256, 256, 256, SB, SB, SB);

    // Heads.
    head_kernel<<<dim3(64), block, 0, stream>>>(F1, w_type, b_type, w_flag,
                                                b_flag, out);
    (void)in_sizes; (void)n_in; (void)out_size; (void)ws_size;
}

// Round 2
// 445.604 us; speedup vs baseline: 1.8745x; 1.8745x over previous
//
#include <hip/hip_runtime.h>
#include <math.h>

// ---------------------------------------------------------------------------
// HPFNetCovPool: 1x1 conv (GEMM K=2048) -> covpool -> Newton-Schulz sqrtm
// (5 iters) -> triu-vec -> linear heads.
// Round 2: all GEMMs on MFMA via split-bf16 (hi/lo) 3-term fp32 emulation.
//   - 128x128 tile, 4 waves, each wave 64x64 via 4x4 frags of 16x16x32 bf16
//   - reg-staged LDS with inline fp32->bf16 hi/lo split
//   - XOR swizzle (row&7)<<3 on bf16-element index: conflict-free b128 reads
//   - NS elementwise (0.5*(3I - T)) fused into GEMM epilogue
// ---------------------------------------------------------------------------

typedef __attribute__((ext_vector_type(8))) short bf16x8;
typedef __attribute__((ext_vector_type(4))) float f32x4;

#define TM 128
#define TN 128
#define TK 32

enum { EPI_NONE = 0, EPI_BIAS = 1, EPI_COV = 2, EPI_RNORM = 3,
       EPI_SQRTNORM = 4, EPI_NS = 5 };

__device__ __forceinline__ short bf16_rn(float x) {
    union { float f; unsigned u; } v; v.f = x;
    unsigned r = v.u + 0x7FFFu + ((v.u >> 16) & 1u);
    return (short)(r >> 16);
}
__device__ __forceinline__ float bf16f(short h) {
    union { float f; unsigned u; } v;
    v.u = ((unsigned)(unsigned short)h) << 16;
    return v.f;
}
// element index into a [128][TK] short plane, XOR-swizzled (16B granules)
__device__ __forceinline__ int swz(int row, int k) {
    return ((row << 5) + k) ^ ((row & 7) << 3);
}

// C[b] (256 x 256) = A[b] (256 x K, lda) @ B[b]
// TRANSB=false: B is [K][256] row-major (ldb). TRANSB=true: B is [256][K] (ldb).
template <bool TRANSB, int EPI>
__global__ __launch_bounds__(256) void gemm_mfma(
    const float* __restrict__ A, const float* __restrict__ B,
    float* __restrict__ C, const float* __restrict__ aux,
    int K, int lda, int ldb,
    long long strideA, long long strideB, long long strideC)
{
    __shared__ __align__(16) short AsH[TM * TK];
    __shared__ __align__(16) short AsL[TM * TK];
    __shared__ __align__(16) short BsH[TN * TK];
    __shared__ __align__(16) short BsL[TN * TK];

    const int bz = blockIdx.z;
    const float* Ab = A + (size_t)bz * strideA;
    const float* Bb = B + (size_t)bz * strideB;
    float* Cb = C + (size_t)bz * strideC;

    const int tid = threadIdx.x;
    const int ib = blockIdx.y * TM, jb = blockIdx.x * TN;
    const int lane = tid & 63, w = tid >> 6;
    const int wr = w >> 1, wc = w & 1;             // 2x2 wave grid
    const int fr = lane & 15, ko = (lane >> 4) << 3;

    f32x4 acc[4][4];
#pragma unroll
    for (int m = 0; m < 4; ++m)
#pragma unroll
        for (int n = 0; n < 4; ++n) acc[m][n] = (f32x4){0.f, 0.f, 0.f, 0.f};

    // staging assignments
    const int srow = tid >> 1;              // 0..127 (A rows / TRANSB-B rows)
    const int skh  = (tid & 1) << 4;        // 0 or 16 (k half)
    const int bn   = tid & 127;             // NOTRANS B: n
    const int bkh  = (tid >> 7) << 4;       // NOTRANS B: k half

    for (int kb = 0; kb < K; kb += TK) {
        // ---------------- stage A (row-major [row][k], k-contiguous) -------
        {
            const float* src = Ab + (size_t)(ib + srow) * lda + kb + skh;
            float x[16];
#pragma unroll
            for (int q = 0; q < 4; ++q) {
                const float4 v = *reinterpret_cast<const float4*>(src + q * 4);
                x[q * 4 + 0] = v.x; x[q * 4 + 1] = v.y;
                x[q * 4 + 2] = v.z; x[q * 4 + 3] = v.w;
            }
            short h[16], l[16];
#pragma unroll
            for (int q = 0; q < 16; ++q) {
                h[q] = bf16_rn(x[q]);
                l[q] = bf16_rn(x[q] - bf16f(h[q]));
            }
            *reinterpret_cast<bf16x8*>(&AsH[swz(srow, skh)])     = *reinterpret_cast<bf16x8*>(&h[0]);
            *reinterpret_cast<bf16x8*>(&AsH[swz(srow, skh + 8)]) = *reinterpret_cast<bf16x8*>(&h[8]);
            *reinterpret_cast<bf16x8*>(&AsL[swz(srow, skh)])     = *reinterpret_cast<bf16x8*>(&l[0]);
            *reinterpret_cast<bf16x8*>(&AsL[swz(srow, skh + 8)]) = *reinterpret_cast<bf16x8*>(&l[8]);
        }
        // ---------------- stage B ------------------------------------------
        if (TRANSB) {
            // B stored [n][k]: same pattern as A
            const float* src = Bb + (size_t)(jb + srow) * ldb + kb + skh;
            float x[16];
#pragma unroll
            for (int q = 0; q < 4; ++q) {
                const float4 v = *reinterpret_cast<const float4*>(src + q * 4);
                x[q * 4 + 0] = v.x; x[q * 4 + 1] = v.y;
                x[q * 4 + 2] = v.z; x[q * 4 + 3] = v.w;
            }
            short h[16], l[16];
#pragma unroll
            for (int q = 0; q < 16; ++q) {
                h[q] = bf16_rn(x[q]);
                l[q] = bf16_rn(x[q] - bf16f(h[q]));
            }
            *reinterpret_cast<bf16x8*>(&BsH[swz(srow, skh)])     = *reinterpret_cast<bf16x8*>(&h[0]);
            *reinterpret_cast<bf16x8*>(&BsH[swz(srow, skh + 8)]) = *reinterpret_cast<bf16x8*>(&h[8]);
            *reinterpret_cast<bf16x8*>(&BsL[swz(srow, skh)])     = *reinterpret_cast<bf16x8*>(&l[0]);
            *reinterpret_cast<bf16x8*>(&BsL[swz(srow, skh + 8)]) = *reinterpret_cast<bf16x8*>(&l[8]);
        } else {
            // B stored [k][n]: transpose during staging. Each dword load is
            // wave-coalesced (64 consecutive n).
            float x[16];
#pragma unroll
            for (int j = 0; j < 16; ++j)
                x[j] = Bb[(size_t)(kb + bkh + j) * ldb + jb + bn];
            short h[16], l[16];
#pragma unroll
            for (int q = 0; q < 16; ++q) {
                h[q] = bf16_rn(x[q]);
                l[q] = bf16_rn(x[q] - bf16f(h[q]));
            }
            *reinterpret_cast<bf16x8*>(&BsH[swz(bn, bkh)])     = *reinterpret_cast<bf16x8*>(&h[0]);
            *reinterpret_cast<bf16x8*>(&BsH[swz(bn, bkh + 8)]) = *reinterpret_cast<bf16x8*>(&h[8]);
            *reinterpret_cast<bf16x8*>(&BsL[swz(bn, bkh)])     = *reinterpret_cast<bf16x8*>(&l[0]);
            *reinterpret_cast<bf16x8*>(&BsL[swz(bn, bkh + 8)]) = *reinterpret_cast<bf16x8*>(&l[8]);
        }
        __syncthreads();

        // ---------------- fragments + MFMA ---------------------------------
        bf16x8 aH[4], aL[4], bH[4], bL[4];
#pragma unroll
        for (int m = 0; m < 4; ++m) {
            const int r = wr * 64 + m * 16 + fr;
            aH[m] = *reinterpret_cast<const bf16x8*>(&AsH[swz(r, ko)]);
            aL[m] = *reinterpret_cast<const bf16x8*>(&AsL[swz(r, ko)]);
        }
#pragma unroll
        for (int n = 0; n < 4; ++n) {
            const int r = wc * 64 + n * 16 + fr;
            bH[n] = *reinterpret_cast<const bf16x8*>(&BsH[swz(r, ko)]);
            bL[n] = *reinterpret_cast<const bf16x8*>(&BsL[swz(r, ko)]);
        }
#pragma unroll
        for (int m = 0; m < 4; ++m)
#pragma unroll
            for (int n = 0; n < 4; ++n) {
                f32x4 c = acc[m][n];
                c = __builtin_amdgcn_mfma_f32_16x16x32_bf16(aH[m], bH[n], c, 0, 0, 0);
                c = __builtin_amdgcn_mfma_f32_16x16x32_bf16(aH[m], bL[n], c, 0, 0, 0);
                c = __builtin_amdgcn_mfma_f32_16x16x32_bf16(aL[m], bH[n], c, 0, 0, 0);
                acc[m][n] = c;
            }
        __syncthreads();
    }

    // ---------------- epilogue ---------------------------------------------
    float scale = 1.0f;
    if constexpr (EPI == EPI_RNORM)    scale = 1.0f / aux[bz];
    if constexpr (EPI == EPI_SQRTNORM) scale = sqrtf(aux[bz]);
    const float* mub = nullptr;
    if constexpr (EPI == EPI_COV) mub = aux + (size_t)bz * 256;

    const int r0 = (lane >> 4) << 2;
#pragma unroll
    for (int m = 0; m < 4; ++m) {
#pragma unroll
        for (int j = 0; j < 4; ++j) {
            const int gi = ib + wr * 64 + m * 16 + r0 + j;
#pragma unroll
            for (int n = 0; n < 4; ++n) {
                const int gj = jb + wc * 64 + n * 16 + fr;
                float v = acc[m][n][j];
                if constexpr (EPI == EPI_BIAS) {
                    v += aux[gi];
                } else if constexpr (EPI == EPI_COV) {
                    v = v * (1.f / 256.f) - mub[gi] * mub[gj];
                } else if constexpr (EPI == EPI_NS) {
                    v = 0.5f * ((gi == gj ? 3.f : 0.f) - v);
                } else if constexpr (EPI == EPI_RNORM || EPI == EPI_SQRTNORM) {
                    v *= scale;
                }
                Cb[(size_t)gi * 256 + gj] = v;
            }
        }
    }
}

// Row means: mu[b*256+o] = mean_m X[b][o][m]. grid = 64*256 blocks of 64.
__global__ __launch_bounds__(64) void mean_kernel(const float* __restrict__ X,
                                                  float* __restrict__ mu)
{
    const int row = blockIdx.x;
    const int lane = threadIdx.x;
    const float4 v = reinterpret_cast<const float4*>(X + (size_t)row * 256)[lane];
    float s = v.x + v.y + v.z + v.w;
#pragma unroll
    for (int off = 32; off > 0; off >>= 1) s += __shfl_down(s, off);
    if (lane == 0) mu[row] = s * (1.0f / 256.0f);
}

// norm[b] = trace(A[b])
__global__ __launch_bounds__(256) void trace_kernel(const float* __restrict__ A,
                                                    float* __restrict__ norm)
{
    const int b = blockIdx.x;
    const int t = threadIdx.x;
    __shared__ float red[256];
    red[t] = A[(size_t)b * 65536 + (size_t)t * 257];
    __syncthreads();
    for (int off = 128; off > 0; off >>= 1) {
        if (t < off) red[t] += red[t + off];
        __syncthreads();
    }
    if (t == 0) norm[b] = red[0];
}

// ZY0 = 0.5*(3I - A/norm[b])
__global__ __launch_bounds__(256) void zy0_kernel(const float* __restrict__ T,
                                                  float* __restrict__ ZY,
                                                  const float* __restrict__ norm)
{
    const size_t e = ((size_t)blockIdx.x * 256 + threadIdx.x) * 4;
    const int b = (int)(e >> 16);
    const int t = (int)(e & 65535);
    const int i = t >> 8;
    const int j = t & 255;
    const float scale = 1.0f / norm[b];
    float4 v = *reinterpret_cast<const float4*>(T + e);
    v.x = 0.5f * ((i == j + 0 ? 3.f : 0.f) - v.x * scale);
    v.y = 0.5f * ((i == j + 1 ? 3.f : 0.f) - v.y * scale);
    v.z = 0.5f * ((i == j + 2 ? 3.f : 0.f) - v.z * scale);
    v.w = 0.5f * ((i == j + 3 ? 3.f : 0.f) - v.w * scale);
    *reinterpret_cast<float4*>(ZY + e) = v;
}

// Heads: grid (64 batches, 5 outputs). Each block: triu-vec dot one weight row.
__global__ __launch_bounds__(256) void head_kernel(
    const float* __restrict__ S, const float* __restrict__ w_type,
    const float* __restrict__ b_type, const float* __restrict__ w_flag,
    const float* __restrict__ b_flag, float* __restrict__ out)
{
    const int b = blockIdx.x;
    const int v = blockIdx.y;
    const int tid = threadIdx.x;
    const float* Sb = S + (size_t)b * 65536;
    const float* w = (v < 4) ? (w_type + (size_t)v * 32896) : w_flag;
    float acc = 0.f;
    int off = 0;
    for (int r = 0; r < 256; ++r) {
        const int L = 256 - r;
        const float* srow = Sb + (size_t)r * 257;
        const float* wrow = w + off;
        for (int idx = tid; idx < L; idx += 256)
            acc = fmaf(srow[idx], wrow[idx], acc);
        off += L;
    }
    __shared__ float red[256];
    red[tid] = acc;
    __syncthreads();
    for (int o = 128; o > 0; o >>= 1) {
        if (tid < o) red[tid] += red[tid + o];
        __syncthreads();
    }
    if (tid == 0) {
        if (v < 4) out[b * 4 + v] = red[0] + b_type[v];
        else       out[256 + b]  = red[0] + b_flag[0];
    }
}

extern "C" void kernel_launch(void* const* d_in, const int* in_sizes, int n_in,
                              void* d_out, int out_size, void* d_ws, size_t ws_size,
                              hipStream_t stream)
{
    const float* features = (const float*)d_in[0];  // [64,2048,16,16]
    const float* w_bn     = (const float*)d_in[1];  // [256,2048]
    const float* b_bn     = (const float*)d_in[2];  // [256]
    const float* w_type   = (const float*)d_in[3];  // [4,32896]
    const float* b_type   = (const float*)d_in[4];  // [4]
    const float* w_flag   = (const float*)d_in[5];  // [1,32896]
    const float* b_flag   = (const float*)d_in[6];  // [1]
    float* out = (float*)d_out;                     // 320 = 64*4 + 64

    const size_t S = 64ull * 256 * 256;
    float* W0 = (float*)d_ws;
    float* W1 = W0 + S;
    float* W2 = W1 + S;
    float* W3 = W2 + S;
    float* mu   = W3 + S;
    float* norm = mu + 64 * 256;

    const dim3 block(256);
    const dim3 gg(256 / TN, 256 / TM, 64);  // (2,2,64)
    const long long SB = 65536;

    // 1. Conv 1x1: X(W0)[b] = w_bn @ F[b] + b_bn.  K=2048.
    gemm_mfma<false, EPI_BIAS><<<gg, block, 0, stream>>>(
        w_bn, features, W0, b_bn, 2048, 2048, 256, 0, 2048LL * 256, SB);
    // 2. Row means of X.
    mean_kernel<<<dim3(64 * 256), dim3(64), 0, stream>>>(W0, mu);
    // 3. Cov: A(W1) = X@X^T/256 - mu mu^T.   (B = X stored [n][k])
    gemm_mfma<true, EPI_COV><<<gg, block, 0, stream>>>(
        W0, W0, W1, mu, 256, 256, 256, SB, SB, SB);
    // 4. norm[b] = trace(A[b]).
    trace_kernel<<<dim3(64), block, 0, stream>>>(W1, norm);
    // 5. ZY0(W2) = 0.5*(3I - A/norm).  (= Z0)
    zy0_kernel<<<dim3(4096), block, 0, stream>>>(W1, W2, norm);
    // 6. Y0(W3) = (A @ ZY0)/norm.
    gemm_mfma<false, EPI_RNORM><<<gg, block, 0, stream>>>(
        W1, W2, W3, norm, 256, 256, 256, SB, SB, SB);

    float* Y = W3;
    float* Z = W2;
    float* F0 = W0;  // per-iter temp (ZY)
    float* F1 = W1;  // per-iter new-Y target
    for (int it = 0; it < 3; ++it) {
        // ZY(F0) = 0.5*(3I - Z@Y)   [NS transform fused in epilogue]
        gemm_mfma<false, EPI_NS><<<gg, block, 0, stream>>>(
            Z, Y, F0, nullptr, 256, 256, 256, SB, SB, SB);
        // Ynew(F1) = Y @ ZY ; Znew(old Y buffer) = ZY @ Z.
        gemm_mfma<false, EPI_NONE><<<gg, block, 0, stream>>>(
            Y, F0, F1, nullptr, 256, 256, 256, SB, SB, SB);
        gemm_mfma<false, EPI_NONE><<<gg, block, 0, stream>>>(
            F0, Z, Y, nullptr, 256, 256, 256, SB, SB, SB);
        float* newY = F1;
        float* newZ = Y;
        float* oldZ = Z;
        Y = newY; Z = newZ; F1 = oldZ;
    }

    // Final: E(F0) = 0.5*(3I - Z@Y) ; S(F1) = (Y @ E) * sqrt(norm).
    gemm_mfma<false, EPI_NS><<<gg, block, 0, stream>>>(
        Z, Y, F0, nullptr, 256, 256, 256, SB, SB, SB);
    gemm_mfma<false, EPI_SQRTNORM><<<gg, block, 0, stream>>>(
        Y, F0, F1, norm, 256, 256, 256, SB, SB, SB);

    // Heads.
    head_kernel<<<dim3(64, 5), block, 0, stream>>>(F1, w_type, b_type, w_flag,
                                                   b_flag, out);
    (void)in_sizes; (void)n_in; (void)out_size; (void)ws_size;
}

// Round 3
// 393.889 us; speedup vs baseline: 2.1206x; 1.1313x over previous
//
#include <hip/hip_runtime.h>
#include <math.h>

// ---------------------------------------------------------------------------
// HPFNetCovPool round 3.
// bf16 hi/lo split is now a STORAGE FORMAT:
//   fmt: [batch][kt(=k/32)][row(256)][128 bytes], 128B row = 8 slots of 16B:
//        slot_log = plane*4 + ((k&31)>>3), stored at slot_log ^ (row&7)  (XOR
//        swizzle baked into global layout so global_load_lds stays linear and
//        ds_read_b128 fragment reads are conflict-free).
// All NS matrices are symmetric (polynomials of cov) -> every GEMM is A@B^T
// with identical A/B staging, outputs written "transposed" (== itself) which
// makes epilogue h/l quads k-consecutive -> packed 8B stores.
// ---------------------------------------------------------------------------

typedef __attribute__((ext_vector_type(8))) short bf16x8;
typedef __attribute__((ext_vector_type(4))) float f32x4;
typedef __attribute__((ext_vector_type(4))) unsigned u32x4;
typedef __attribute__((ext_vector_type(2))) unsigned u32x2;

enum { E_BIAS = 0, E_COV = 1, E_T = 2, E_TNS = 3, E_SF32 = 4 };

__device__ __forceinline__ unsigned fbits(float f) { union { float f; unsigned u; } x; x.f = f; return x.u; }
__device__ __forceinline__ float bitsf(unsigned u) { union { float f; unsigned u; } x; x.u = u; return x.f; }
__device__ __forceinline__ float bf16v(short h) { return bitsf(((unsigned)(unsigned short)h) << 16); }

// async global->LDS, 16B per lane. LDS dest must be wave-uniform base; HW
// writes base + lane*16. Global src is per-lane.
__device__ __forceinline__ void gld16(const void* g, void* l) {
  __builtin_amdgcn_global_load_lds(
      (const __attribute__((address_space(1))) void*)(size_t)(g),
      (__attribute__((address_space(3))) void*)(unsigned)(size_t)(l), 16, 0, 0);
}

// truncation split: h = top16(v), l = top16(v - h). |err| <= 2^-16 |v|.
__device__ __forceinline__ unsigned pack_h(float a, float b) {
  return (fbits(a) >> 16) | (fbits(b) & 0xFFFF0000u);
}
__device__ __forceinline__ unsigned pack_l(float a, float b) {
  float la = a - bitsf(fbits(a) & 0xFFFF0000u);
  float lb = b - bitsf(fbits(b) & 0xFFFF0000u);
  return (fbits(la) >> 16) | (fbits(lb) & 0xFFFF0000u);
}

// ---------------------------------------------------------------------------
// C[b](256x256) = A[b] @ B[b]^T, A/B in fmt (CONVB: B = raw fp32 features).
// TM x 64 tile, TM*2 threads (TM/32 waves of 64x32 output each).
template <int TM, bool CONVB, int EPI, bool PAIR>
__global__ __launch_bounds__(TM * 2, 2) void gemm_k(
    const char* __restrict__ A1, const char* __restrict__ B1v, char* __restrict__ C1,
    const char* __restrict__ A2, const char* __restrict__ B2v, char* __restrict__ C2,
    char* __restrict__ Cz, const float* __restrict__ aux,
    const float* __restrict__ nrmv, float* __restrict__ Cf,
    int K, long long sAb, long long sBb)
{
  constexpr int NW = TM / 32;           // waves per block
  constexpr int BUFSZ = (TM + 64) * 128;
  __shared__ char lds[2 * BUFSZ];

  const int tid = threadIdx.x, lane = tid & 63, w = tid >> 6;
  const int wr = w >> 1, wc = w & 1, fr = lane & 15, g = lane >> 4;
  int bz = blockIdx.z;
  const char* Ab = A1; const char* Bb = B1v; char* Cb = C1;
  if (PAIR && bz >= 64) { bz -= 64; Ab = A2; Bb = B2v; Cb = C2; }
  Ab += (size_t)bz * sAb;
  const char* Bby = Bb + (size_t)bz * sBb;                    // fmt B
  const float* Ff = (const float*)Bb + (size_t)bz * 524288;   // conv F [2048][256]
  const int ib = blockIdx.y * TM, jb = blockIdx.x * 64;

  f32x4 acc[4][2];
#pragma unroll
  for (int m = 0; m < 4; ++m)
#pragma unroll
    for (int n = 0; n < 2; ++n) acc[m][n] = (f32x4){0.f, 0.f, 0.f, 0.f};

  float xv[8];
  const int NT = K >> 5;

  auto stage = [&](int t, int c) {
    char* lA = lds + c * BUFSZ;
    char* lB = lA + TM * 128;
    const char* Ag = Ab + (size_t)t * 32768 + (size_t)ib * 128;
    constexpr int IA = TM / 8;
    if (!CONVB) {
      const char* Bg = Bby + (size_t)t * 32768 + (size_t)jb * 128;
      for (int i = w; i < IA + 8; i += NW) {
        if (i < IA) gld16(Ag + i * 1024 + lane * 16, lA + i * 1024);
        else        gld16(Bg + (i - IA) * 1024 + lane * 16, lB + (i - IA) * 1024);
      }
    } else {
      for (int i = w; i < IA; i += NW) gld16(Ag + i * 1024 + lane * 16, lA + i * 1024);
      // B: coalesced fp32 loads, lane = pixel row, wave = k-octet
      const float* src = Ff + ((size_t)t * 32 + w * 8) * 256 + jb + lane;
#pragma unroll
      for (int e = 0; e < 8; ++e) xv[e] = src[e * 256];
    }
  };

  auto convb_commit = [&](int c) {
    char* lB = lds + c * BUFSZ + TM * 128;
    const int m = lane;
    u32x4 hq = (u32x4){pack_h(xv[0], xv[1]), pack_h(xv[2], xv[3]),
                       pack_h(xv[4], xv[5]), pack_h(xv[6], xv[7])};
    u32x4 lq = (u32x4){pack_l(xv[0], xv[1]), pack_l(xv[2], xv[3]),
                       pack_l(xv[4], xv[5]), pack_l(xv[6], xv[7])};
    *(u32x4*)(lB + m * 128 + ((w ^ (m & 7)) << 4)) = hq;
    *(u32x4*)(lB + m * 128 + (((w + 4) ^ (m & 7)) << 4)) = lq;
  };

  auto compute = [&](int c) {
    const char* lA = lds + c * BUFSZ;
    const char* lB = lA + TM * 128;
    bf16x8 aH[4], aL[4], bH[2], bL[2];
#pragma unroll
    for (int m = 0; m < 4; ++m) {
      const int r = wr * 64 + m * 16 + fr;
      const char* p = lA + r * 128;
      aH[m] = *(const bf16x8*)(p + ((g ^ (r & 7)) << 4));
      aL[m] = *(const bf16x8*)(p + (((g + 4) ^ (r & 7)) << 4));
    }
#pragma unroll
    for (int n = 0; n < 2; ++n) {
      const int r = wc * 32 + n * 16 + fr;
      const char* p = lB + r * 128;
      bH[n] = *(const bf16x8*)(p + ((g ^ (r & 7)) << 4));
      bL[n] = *(const bf16x8*)(p + (((g + 4) ^ (r & 7)) << 4));
    }
#pragma unroll
    for (int m = 0; m < 4; ++m)
#pragma unroll
      for (int n = 0; n < 2; ++n) {
        f32x4 cA = acc[m][n];
        cA = __builtin_amdgcn_mfma_f32_16x16x32_bf16(aL[m], bH[n], cA, 0, 0, 0);
        cA = __builtin_amdgcn_mfma_f32_16x16x32_bf16(aH[m], bL[n], cA, 0, 0, 0);
        cA = __builtin_amdgcn_mfma_f32_16x16x32_bf16(aH[m], bH[n], cA, 0, 0, 0);
        acc[m][n] = cA;
      }
  };

  stage(0, 0);
  if (CONVB) convb_commit(0);
  __syncthreads();
  for (int t = 0; t < NT; ++t) {
    const int cur = t & 1;
    if (t + 1 < NT) stage(t + 1, cur ^ 1);   // loads fly under MFMA
    compute(cur);
    if (CONVB && t + 1 < NT) convb_commit(cur ^ 1);
    __syncthreads();                          // vmcnt(0)+lgkm drain + barrier
  }

  // ----------------------------- epilogue ---------------------------------
  const int r0 = g << 2;
  char* Cbb = Cb + (size_t)bz * 262144;
  char* Czb = (EPI == E_COV) ? (Cz + (size_t)bz * 262144) : nullptr;
  float rn = 0.f, sq = 0.f;
  if (EPI == E_COV)  rn = 1.0f / nrmv[bz];
  if (EPI == E_SF32) sq = sqrtf(nrmv[bz]);

#pragma unroll
  for (int m = 0; m < 4; ++m) {
    const int gi0 = ib + wr * 64 + m * 16 + r0;
#pragma unroll
    for (int n = 0; n < 2; ++n) {
      const int gj = jb + wc * 32 + n * 16 + fr;
      if (EPI == E_BIAS) {
        // row-major fmt write of X: row = gi, k = gj (conv output not symmetric)
        const int ktj = gj >> 5, sj = (gj & 31) >> 3, bo = (gj & 7) * 2;
#pragma unroll
        for (int j = 0; j < 4; ++j) {
          const int gi = gi0 + j;
          char* rp = Cbb + (size_t)ktj * 32768 + (size_t)gi * 128;
          const float v = acc[m][n][j] + aux[gi];
          const unsigned u = fbits(v);
          *(short*)(rp + ((sj ^ (gi & 7)) << 4) + bo) = (short)(u >> 16);
          const float lf = v - bitsf(u & 0xFFFF0000u);
          *(short*)(rp + (((sj + 4) ^ (gi & 7)) << 4) + bo) = (short)(fbits(lf) >> 16);
        }
      } else {
        float vv[4];
#pragma unroll
        for (int j = 0; j < 4; ++j) {
          const int gi = gi0 + j;
          float v = acc[m][n][j];
          if (EPI == E_COV) v = v * (1.f / 256.f) - aux[bz * 256 + gi] * aux[bz * 256 + gj];
          if (EPI == E_TNS) v = 0.5f * ((gi == gj ? 3.f : 0.f) - v);
          if (EPI == E_SF32) v = v * sq;
          if (EPI == E_COV) v = v * rn;          // An = cov/norm
          vv[j] = v;
        }
        if (EPI == E_SF32) {
          *(f32x4*)(Cf + (size_t)bz * 65536 + (size_t)gj * 256 + gi0) =
              (f32x4){vv[0], vv[1], vv[2], vv[3]};
        } else {
          // transposed fmt write (valid: symmetric product): row = gj, k = gi
          const int kt = gi0 >> 5, s = (gi0 & 31) >> 3, bo = (gi0 & 7) * 2;
          char* rp = Cbb + (size_t)kt * 32768 + (size_t)gj * 128;
          *(u32x2*)(rp + ((s ^ (gj & 7)) << 4) + bo) =
              (u32x2){pack_h(vv[0], vv[1]), pack_h(vv[2], vv[3])};
          *(u32x2*)(rp + (((s + 4) ^ (gj & 7)) << 4) + bo) =
              (u32x2){pack_l(vv[0], vv[1]), pack_l(vv[2], vv[3])};
          if (EPI == E_COV) {
            float zz[4];
#pragma unroll
            for (int j = 0; j < 4; ++j)
              zz[j] = (gi0 + j == gj ? 1.5f : 0.f) - 0.5f * vv[j];
            char* zp = Czb + (size_t)kt * 32768 + (size_t)gj * 128;
            *(u32x2*)(zp + ((s ^ (gj & 7)) << 4) + bo) =
                (u32x2){pack_h(zz[0], zz[1]), pack_h(zz[2], zz[3])};
            *(u32x2*)(zp + (((s + 4) ^ (gj & 7)) << 4) + bo) =
                (u32x2){pack_l(zz[0], zz[1]), pack_l(zz[2], zz[3])};
          }
        }
      }
    }
  }
}

// ---------------------------------------------------------------------------
// w_bn [256][2048] fp32 -> fmt (rows already k-contiguous; no transpose).
__global__ __launch_bounds__(256) void cvt_w(const float* __restrict__ wsrc,
                                             char* __restrict__ Wf)
{
  const int kt = blockIdx.x, r = threadIdx.x;
  const float* src = wsrc + (size_t)r * 2048 + kt * 32;
  char* rp = Wf + (size_t)kt * 32768 + (size_t)r * 128;
#pragma unroll
  for (int s = 0; s < 4; ++s) {
    float x[8];
#pragma unroll
    for (int e = 0; e < 8; ++e) x[e] = src[s * 8 + e];
    *(u32x4*)(rp + ((s ^ (r & 7)) << 4)) =
        (u32x4){pack_h(x[0], x[1]), pack_h(x[2], x[3]), pack_h(x[4], x[5]), pack_h(x[6], x[7])};
    *(u32x4*)(rp + (((s + 4) ^ (r & 7)) << 4)) =
        (u32x4){pack_l(x[0], x[1]), pack_l(x[2], x[3]), pack_l(x[4], x[5]), pack_l(x[6], x[7])};
  }
}

// ---------------------------------------------------------------------------
// Per-row mean + trace(cov) = sum_i(ssq_i/256 - mu_i^2), from X in fmt.
__global__ __launch_bounds__(256) void meanvar(const char* __restrict__ X,
                                               float* __restrict__ mu,
                                               float* __restrict__ nrm)
{
  const int b = blockIdx.x, i = threadIdx.x;
  const char* rp0 = X + (size_t)b * 262144 + (size_t)i * 128;
  float s = 0.f, ss = 0.f;
  for (int kt = 0; kt < 8; ++kt) {
    const char* rp = rp0 + kt * 32768;
#pragma unroll
    for (int sl = 0; sl < 4; ++sl) {
      bf16x8 h8 = *(const bf16x8*)(rp + ((sl ^ (i & 7)) << 4));
      bf16x8 l8 = *(const bf16x8*)(rp + (((sl + 4) ^ (i & 7)) << 4));
#pragma unroll
      for (int e = 0; e < 8; ++e) {
        const float v = bf16v(h8[e]) + bf16v(l8[e]);
        s += v; ss += v * v;
      }
    }
  }
  const float m = s * (1.f / 256.f);
  mu[b * 256 + i] = m;
  __shared__ float red[256];
  red[i] = ss * (1.f / 256.f) - m * m;
  __syncthreads();
  for (int o = 128; o > 0; o >>= 1) {
    if (i < o) red[i] += red[i + o];
    __syncthreads();
  }
  if (i == 0) nrm[b] = red[0];
}

// ---------------------------------------------------------------------------
// Heads: grid (64 batches, 5 outputs), triu-vec dot.
__global__ __launch_bounds__(256) void head_kernel(
    const float* __restrict__ S, const float* __restrict__ w_type,
    const float* __restrict__ b_type, const float* __restrict__ w_flag,
    const float* __restrict__ b_flag, float* __restrict__ out)
{
  const int b = blockIdx.x, v = blockIdx.y, tid = threadIdx.x;
  const float* Sb = S + (size_t)b * 65536;
  const float* wgt = (v < 4) ? (w_type + (size_t)v * 32896) : w_flag;
  float acc = 0.f;
  int off = 0;
  for (int r = 0; r < 256; ++r) {
    const int L = 256 - r;
    const float* srow = Sb + (size_t)r * 257;
    const float* wrow = wgt + off;
    for (int idx = tid; idx < L; idx += 256) acc = fmaf(srow[idx], wrow[idx], acc);
    off += L;
  }
  __shared__ float red[256];
  red[tid] = acc;
  __syncthreads();
  for (int o = 128; o > 0; o >>= 1) {
    if (tid < o) red[tid] += red[tid + o];
    __syncthreads();
  }
  if (tid == 0) {
    if (v < 4) out[b * 4 + v] = red[0] + b_type[v];
    else       out[256 + b] = red[0] + b_flag[0];
  }
}

// ---------------------------------------------------------------------------
extern "C" void kernel_launch(void* const* d_in, const int* in_sizes, int n_in,
                              void* d_out, int out_size, void* d_ws, size_t ws_size,
                              hipStream_t stream)
{
  const float* features = (const float*)d_in[0];
  const float* w_bn     = (const float*)d_in[1];
  const float* b_bn     = (const float*)d_in[2];
  const float* w_type   = (const float*)d_in[3];
  const float* b_type   = (const float*)d_in[4];
  const float* w_flag   = (const float*)d_in[5];
  const float* b_flag   = (const float*)d_in[6];
  float* out = (float*)d_out;

  // ws: 5 fmt pool buffers (16.78 MB each), Wfmt 2 MB, mu, norm. ~86 MB.
  char* W = (char*)d_ws;
  const size_t PB = 16777216;
  char* P0 = W;           char* P1 = W + PB;     char* P2 = W + 2 * PB;
  char* P3 = W + 3 * PB;  char* P4 = W + 4 * PB;
  char* Wf = W + 5 * PB;
  float* mu = (float*)(W + 5 * PB + 2097152);
  float* nrm = mu + 64 * 256;
  float* Sf = (float*)P4;  // final S fp32 aliases P4 (dead by then)

  const long long SB = 262144;  // fmt per-batch bytes (K=256)

  cvt_w<<<dim3(64), dim3(256), 0, stream>>>(w_bn, Wf);

  // conv: X = w_bn @ F^T(+bias), K=2048. A=Wfmt (sAb=0), B=raw F.
  gemm_k<128, true, E_BIAS, false><<<dim3(4, 2, 64), dim3(256), 0, stream>>>(
      Wf, (const char*)features, P0, nullptr, nullptr, nullptr, nullptr,
      b_bn, nullptr, nullptr, 2048, 0, 0);

  meanvar<<<dim3(64), dim3(256), 0, stream>>>(P0, mu, nrm);

  // cov -> An (P1) and Z0=ZY0 (P2)
  gemm_k<64, false, E_COV, false><<<dim3(4, 4, 64), dim3(128), 0, stream>>>(
      P0, P0, P1, nullptr, nullptr, nullptr, P2, mu, nrm, nullptr, 256, SB, SB);

  // Y0 = An @ ZY0 -> P3
  gemm_k<64, false, E_T, false><<<dim3(4, 4, 64), dim3(128), 0, stream>>>(
      P1, P2, P3, nullptr, nullptr, nullptr, nullptr, nullptr, nullptr, nullptr, 256, SB, SB);

  // it0: ZY = 0.5(3I - Z@Y): Z=P2,Y=P3 -> P4 ; pair: Yn=P3@P4->P0, Zn=P4@P2->P1
  gemm_k<64, false, E_TNS, false><<<dim3(4, 4, 64), dim3(128), 0, stream>>>(
      P2, P3, P4, nullptr, nullptr, nullptr, nullptr, nullptr, nullptr, nullptr, 256, SB, SB);
  gemm_k<64, false, E_T, true><<<dim3(4, 4, 128), dim3(128), 0, stream>>>(
      P3, P4, P0, P4, P2, P1, nullptr, nullptr, nullptr, nullptr, 256, SB, SB);

  // it1: Z=P1,Y=P0 -> ZY=P2 ; Yn=P0@P2->P3, Zn=P2@P1->P4
  gemm_k<64, false, E_TNS, false><<<dim3(4, 4, 64), dim3(128), 0, stream>>>(
      P1, P0, P2, nullptr, nullptr, nullptr, nullptr, nullptr, nullptr, nullptr, 256, SB, SB);
  gemm_k<64, false, E_T, true><<<dim3(4, 4, 128), dim3(128), 0, stream>>>(
      P0, P2, P3, P2, P1, P4, nullptr, nullptr, nullptr, nullptr, 256, SB, SB);

  // it2: Z=P4,Y=P3 -> ZY=P0 ; Yn=P3@P0->P1, Zn=P0@P4->P2
  gemm_k<64, false, E_TNS, false><<<dim3(4, 4, 64), dim3(128), 0, stream>>>(
      P4, P3, P0, nullptr, nullptr, nullptr, nullptr, nullptr, nullptr, nullptr, 256, SB, SB);
  gemm_k<64, false, E_T, true><<<dim3(4, 4, 128), dim3(128), 0, stream>>>(
      P3, P0, P1, P0, P4, P2, nullptr, nullptr, nullptr, nullptr, 256, SB, SB);

  // final: E = 0.5(3I - Z@Y): Z=P2,Y=P1 -> P3 ; S = (Y @ E)*sqrt(norm) -> Sf(P4)
  gemm_k<64, false, E_TNS, false><<<dim3(4, 4, 64), dim3(128), 0, stream>>>(
      P2, P1, P3, nullptr, nullptr, nullptr, nullptr, nullptr, nullptr, nullptr, 256, SB, SB);
  gemm_k<64, false, E_SF32, false><<<dim3(4, 4, 64), dim3(128), 0, stream>>>(
      P1, P3, nullptr, nullptr, nullptr, nullptr, nullptr, nullptr, nrm, Sf, 256, SB, SB);

  head_kernel<<<dim3(64, 5), dim3(256), 0, stream>>>(Sf, w_type, b_type, w_flag,
                                                     b_flag, out);
  (void)in_sizes; (void)n_in; (void)out_size; (void)ws_size;
}

// Round 4
// 335.597 us; speedup vs baseline: 2.4889x; 1.1737x over previous
//
#include <hip/hip_runtime.h>
#include <math.h>

// ---------------------------------------------------------------------------
// HPFNetCovPool round 4.
//  - fmt storage: [batch][kt=k/32][row(256)][128B]; 128B = 8x16B slots,
//    slot_log = plane*4 + ((k&31)>>3), stored at slot_log ^ (row&7).
//  - conv: A=Wf via global_load_lds (3-buf counted-vmcnt pipeline),
//    B=features direct global->reg->h/l pack (no LDS for B).
//  - NS GEMMs: all operands/products symmetric -> triangle tiles (10/16)
//    with mirrored writes. Same 3-buf counted-vmcnt pipeline.
//  - heads: dense dot with precomputed full-matrix W2 (tri weights halved).
// ---------------------------------------------------------------------------

typedef __attribute__((ext_vector_type(8))) short bf16x8;
typedef __attribute__((ext_vector_type(4))) float f32x4;
typedef __attribute__((ext_vector_type(4))) unsigned u32x4;
typedef __attribute__((ext_vector_type(2))) unsigned u32x2;

enum { E_T = 0, E_TNS = 1, E_COV = 2, E_SF32 = 3 };

__device__ __forceinline__ unsigned fbits(float f) { union { float f; unsigned u; } x; x.f = f; return x.u; }
__device__ __forceinline__ float bitsf(unsigned u) { union { float f; unsigned u; } x; x.u = u; return x.f; }
__device__ __forceinline__ float bf16v(short h) { return bitsf(((unsigned)(unsigned short)h) << 16); }

__device__ __forceinline__ unsigned pack_h(float a, float b) {
  return (fbits(a) >> 16) | (fbits(b) & 0xFFFF0000u);
}
__device__ __forceinline__ unsigned pack_l(float a, float b) {
  float la = a - bitsf(fbits(a) & 0xFFFF0000u);
  float lb = b - bitsf(fbits(b) & 0xFFFF0000u);
  return (fbits(la) >> 16) | (fbits(lb) & 0xFFFF0000u);
}

__device__ __forceinline__ void gld16(const void* g, void* l) {
  __builtin_amdgcn_global_load_lds(
      (const __attribute__((address_space(1))) void*)(size_t)(g),
      (__attribute__((address_space(3))) void*)(unsigned)(size_t)(l), 16, 0, 0);
}

#define WAIT_VM(N) asm volatile("s_waitcnt vmcnt(" #N ")" ::: "memory")
#define BARRIER() do { __builtin_amdgcn_s_barrier(); asm volatile("" ::: "memory"); } while (0)

// ---------------------------------------------------------------------------
// conv: X[b](256ch x 256pix) = w_bn(fmt) @ F[b] + bias -> X in fmt
// grid (4 jtiles, 2 itiles, 64 batch), 256 threads (4 waves, 2x2).
__global__ __launch_bounds__(256) void conv_k(
    const char* __restrict__ Wf, const float* __restrict__ F,
    char* __restrict__ X, const float* __restrict__ bias)
{
  __shared__ __align__(16) char lds[3 * 16384];
  const int tid = threadIdx.x, lane = tid & 63, w = tid >> 6;
  const int wr = w >> 1, wc = w & 1, fr = lane & 15, g = lane >> 4;
  const int bz = blockIdx.z, ib = blockIdx.y * 128, jb = blockIdx.x * 64;
  const float* Fb = F + (size_t)bz * 524288;

  f32x4 acc[4][2] = {};
  float xv[16];

  auto stageA = [&](int t) {
    const char* Ag = Wf + (size_t)t * 32768 + (size_t)ib * 128;
    char* lA = lds + (t % 3) * 16384;
#pragma unroll
    for (int i = 0; i < 4; ++i)
      gld16(Ag + (w + i * 4) * 1024 + lane * 16, lA + (w + i * 4) * 1024);
  };
  auto loadB = [&](int t) {
    const float* src = Fb + ((size_t)t * 32 + g * 8) * 256 + jb + wc * 32 + fr;
#pragma unroll
    for (int n = 0; n < 2; ++n)
#pragma unroll
      for (int e = 0; e < 8; ++e)
        xv[n * 8 + e] = src[e * 256 + n * 16];
  };

  stageA(0); stageA(1); loadB(0);

  for (int t = 0; t < 64; ++t) {
    if (t < 63) { WAIT_VM(20); } else { WAIT_VM(0); }
    BARRIER();
    if (t + 2 < 64) stageA(t + 2);
    // pack B(t) h/l fragments
    bf16x8 bH[2], bL[2];
#pragma unroll
    for (int n = 0; n < 2; ++n) {
      short hh[8], ll[8];
#pragma unroll
      for (int e = 0; e < 8; ++e) {
        const float v = xv[n * 8 + e];
        const unsigned u = fbits(v);
        hh[e] = (short)(u >> 16);
        ll[e] = (short)(fbits(v - bitsf(u & 0xFFFF0000u)) >> 16);
      }
      bH[n] = *(bf16x8*)hh; bL[n] = *(bf16x8*)ll;
    }
    if (t + 1 < 64) loadB(t + 1);
    const char* lA = lds + (t % 3) * 16384;
    bf16x8 aH[4], aL[4];
#pragma unroll
    for (int m = 0; m < 4; ++m) {
      const int r = wr * 64 + m * 16 + fr;
      const char* p = lA + r * 128;
      aH[m] = *(const bf16x8*)(p + ((g ^ (r & 7)) << 4));
      aL[m] = *(const bf16x8*)(p + (((g + 4) ^ (r & 7)) << 4));
    }
#pragma unroll
    for (int m = 0; m < 4; ++m)
#pragma unroll
      for (int n = 0; n < 2; ++n) {
        f32x4 c = acc[m][n];
        c = __builtin_amdgcn_mfma_f32_16x16x32_bf16(aL[m], bH[n], c, 0, 0, 0);
        c = __builtin_amdgcn_mfma_f32_16x16x32_bf16(aH[m], bL[n], c, 0, 0, 0);
        c = __builtin_amdgcn_mfma_f32_16x16x32_bf16(aH[m], bH[n], c, 0, 0, 0);
        acc[m][n] = c;
      }
  }

  // epilogue: X fmt row = channel gi, k = pixel gj
  char* Xb = X + (size_t)bz * 262144;
#pragma unroll
  for (int m = 0; m < 4; ++m) {
    const int gi0 = ib + wr * 64 + m * 16 + g * 4;
#pragma unroll
    for (int n = 0; n < 2; ++n) {
      const int gj = jb + wc * 32 + n * 16 + fr;
      const int ktj = gj >> 5, sj = (gj & 31) >> 3, bo = (gj & 7) * 2;
#pragma unroll
      for (int j = 0; j < 4; ++j) {
        const int gi = gi0 + j;
        char* rp = Xb + (size_t)ktj * 32768 + (size_t)gi * 128;
        const float v = acc[m][n][j] + bias[gi];
        const unsigned u = fbits(v);
        *(short*)(rp + ((sj ^ (gi & 7)) << 4) + bo) = (short)(u >> 16);
        *(short*)(rp + (((sj + 4) ^ (gi & 7)) << 4) + bo) =
            (short)(fbits(v - bitsf(u & 0xFFFF0000u)) >> 16);
      }
    }
  }
}

// ---------------------------------------------------------------------------
// Symmetric fmt x fmt -> fmt GEMM on triangle tiles. C = A @ B^T (all matrices
// symmetric, commuting). Block: 128 thr (2 waves), tile 64x64, K=256 (8 steps).
template <int EPI, bool PAIR>
__global__ __launch_bounds__(128) void gemm_s(
    const char* __restrict__ A1, const char* __restrict__ B1, char* __restrict__ C1,
    const char* __restrict__ A2, const char* __restrict__ B2, char* __restrict__ C2,
    char* __restrict__ Cz, const float* __restrict__ mu,
    const float* __restrict__ nrm, float* __restrict__ Cf)
{
  static const int TIa[10] = {0, 0, 0, 0, 1, 1, 1, 2, 2, 3};
  static const int TJa[10] = {0, 1, 2, 3, 1, 2, 3, 2, 3, 3};
  __shared__ __align__(16) char lds[3 * 16384];
  const int tid = threadIdx.x, lane = tid & 63, w = tid >> 6;  // w = col-half
  const int fr = lane & 15, g = lane >> 4;
  int bz = blockIdx.z;
  const char* Ab; const char* Bb; char* Cb;
  if (PAIR && bz >= 64) { bz -= 64; Ab = A2; Bb = B2; Cb = C2; }
  else { Ab = A1; Bb = B1; Cb = C1; }
  Ab += (size_t)bz * 262144; Bb += (size_t)bz * 262144; Cb += (size_t)bz * 262144;
  const int bi = TIa[blockIdx.x], bj = TJa[blockIdx.x];
  const int ib = bi * 64, jb = bj * 64;

  f32x4 acc[4][2] = {};

  auto stage = [&](int t) {
    char* lA = lds + (t % 3) * 16384;
    const char* Ag = Ab + (size_t)t * 32768 + (size_t)ib * 128;
    const char* Bg = Bb + (size_t)t * 32768 + (size_t)jb * 128;
#pragma unroll
    for (int i = 0; i < 8; ++i) {
      const int s = w + i * 2;
      if (s < 8) gld16(Ag + s * 1024 + lane * 16, lA + s * 1024);
      else       gld16(Bg + (s - 8) * 1024 + lane * 16, lA + 8192 + (s - 8) * 1024);
    }
  };

  stage(0); stage(1);
  for (int t = 0; t < 8; ++t) {
    if (t < 7) { WAIT_VM(8); } else { WAIT_VM(0); }
    BARRIER();
    if (t + 2 < 8) stage(t + 2);
    const char* lA = lds + (t % 3) * 16384;
    const char* lB = lA + 8192;
    bf16x8 aH[4], aL[4], bH[2], bL[2];
#pragma unroll
    for (int m = 0; m < 4; ++m) {
      const int r = m * 16 + fr;
      const char* p = lA + r * 128;
      aH[m] = *(const bf16x8*)(p + ((g ^ (r & 7)) << 4));
      aL[m] = *(const bf16x8*)(p + (((g + 4) ^ (r & 7)) << 4));
    }
#pragma unroll
    for (int n = 0; n < 2; ++n) {
      const int r = w * 32 + n * 16 + fr;
      const char* p = lB + r * 128;
      bH[n] = *(const bf16x8*)(p + ((g ^ (r & 7)) << 4));
      bL[n] = *(const bf16x8*)(p + (((g + 4) ^ (r & 7)) << 4));
    }
#pragma unroll
    for (int m = 0; m < 4; ++m)
#pragma unroll
      for (int n = 0; n < 2; ++n) {
        f32x4 c = acc[m][n];
        c = __builtin_amdgcn_mfma_f32_16x16x32_bf16(aL[m], bH[n], c, 0, 0, 0);
        c = __builtin_amdgcn_mfma_f32_16x16x32_bf16(aH[m], bL[n], c, 0, 0, 0);
        c = __builtin_amdgcn_mfma_f32_16x16x32_bf16(aH[m], bH[n], c, 0, 0, 0);
        acc[m][n] = c;
      }
  }

  // --------------------------- epilogue ------------------------------------
  const float sq = (EPI == E_SF32) ? sqrtf(nrm[bz]) : 0.f;
  const float rn = (EPI == E_COV) ? 1.0f / nrm[bz] : 0.f;

#pragma unroll
  for (int m = 0; m < 4; ++m) {
    const int gi0 = ib + m * 16 + g * 4;
#pragma unroll
    for (int n = 0; n < 2; ++n) {
      const int gj = jb + w * 32 + n * 16 + fr;
      float vv[4];
#pragma unroll
      for (int j = 0; j < 4; ++j) {
        float v = acc[m][n][j];
        if (EPI == E_COV)
          v = (v * (1.f / 256.f) - mu[bz * 256 + gi0 + j] * mu[bz * 256 + gj]) * rn;
        if (EPI == E_TNS) v = (gi0 + j == gj ? 1.5f : 0.f) - 0.5f * v;
        if (EPI == E_SF32) v = v * sq;
        vv[j] = v;
      }
      if (EPI == E_SF32) {
        *(f32x4*)(Cf + (size_t)bz * 65536 + (size_t)gj * 256 + gi0) =
            (f32x4){vv[0], vv[1], vv[2], vv[3]};
        if (bi != bj) {
#pragma unroll
          for (int j = 0; j < 4; ++j)
            Cf[(size_t)bz * 65536 + (size_t)(gi0 + j) * 256 + gj] = vv[j];
        }
      } else {
        const int kt = gi0 >> 5, s = (gi0 & 31) >> 3, bo = (gi0 & 7) * 2;
        char* rp = Cb + (size_t)kt * 32768 + (size_t)gj * 128;
        *(u32x2*)(rp + ((s ^ (gj & 7)) << 4) + bo) = (u32x2){pack_h(vv[0], vv[1]), pack_h(vv[2], vv[3])};
        *(u32x2*)(rp + (((s + 4) ^ (gj & 7)) << 4) + bo) = (u32x2){pack_l(vv[0], vv[1]), pack_l(vv[2], vv[3])};
        if (bi != bj) {
          const int kt2 = gj >> 5, s2 = (gj & 31) >> 3, bo2 = (gj & 7) * 2;
#pragma unroll
          for (int j = 0; j < 4; ++j) {
            const int gi = gi0 + j;
            char* rp2 = Cb + (size_t)kt2 * 32768 + (size_t)gi * 128;
            const unsigned u = fbits(vv[j]);
            *(short*)(rp2 + ((s2 ^ (gi & 7)) << 4) + bo2) = (short)(u >> 16);
            *(short*)(rp2 + (((s2 + 4) ^ (gi & 7)) << 4) + bo2) =
                (short)(fbits(vv[j] - bitsf(u & 0xFFFF0000u)) >> 16);
          }
        }
        if (EPI == E_COV) {
          float zz[4];
#pragma unroll
          for (int j = 0; j < 4; ++j) zz[j] = (gi0 + j == gj ? 1.5f : 0.f) - 0.5f * vv[j];
          char* zp = Cz + (size_t)bz * 262144 + (size_t)kt * 32768 + (size_t)gj * 128;
          *(u32x2*)(zp + ((s ^ (gj & 7)) << 4) + bo) = (u32x2){pack_h(zz[0], zz[1]), pack_h(zz[2], zz[3])};
          *(u32x2*)(zp + (((s + 4) ^ (gj & 7)) << 4) + bo) = (u32x2){pack_l(zz[0], zz[1]), pack_l(zz[2], zz[3])};
          if (bi != bj) {
            const int kt2 = gj >> 5, s2 = (gj & 31) >> 3, bo2 = (gj & 7) * 2;
#pragma unroll
            for (int j = 0; j < 4; ++j) {
              const int gi = gi0 + j;
              char* zp2 = Cz + (size_t)bz * 262144 + (size_t)kt2 * 32768 + (size_t)gi * 128;
              const unsigned u = fbits(zz[j]);
              *(short*)(zp2 + ((s2 ^ (gi & 7)) << 4) + bo2) = (short)(u >> 16);
              *(short*)(zp2 + (((s2 + 4) ^ (gi & 7)) << 4) + bo2) =
                  (short)(fbits(zz[j] - bitsf(u & 0xFFFF0000u)) >> 16);
            }
          }
        }
      }
    }
  }
}

// ---------------------------------------------------------------------------
// w_bn [256][2048] fp32 -> fmt.
__global__ __launch_bounds__(256) void cvt_w(const float* __restrict__ wsrc,
                                             char* __restrict__ Wf)
{
  const int kt = blockIdx.x, r = threadIdx.x;
  const float* src = wsrc + (size_t)r * 2048 + kt * 32;
  char* rp = Wf + (size_t)kt * 32768 + (size_t)r * 128;
#pragma unroll
  for (int s = 0; s < 4; ++s) {
    float x[8];
#pragma unroll
    for (int e = 0; e < 8; ++e) x[e] = src[s * 8 + e];
    *(u32x4*)(rp + ((s ^ (r & 7)) << 4)) =
        (u32x4){pack_h(x[0], x[1]), pack_h(x[2], x[3]), pack_h(x[4], x[5]), pack_h(x[6], x[7])};
    *(u32x4*)(rp + (((s + 4) ^ (r & 7)) << 4)) =
        (u32x4){pack_l(x[0], x[1]), pack_l(x[2], x[3]), pack_l(x[4], x[5]), pack_l(x[6], x[7])};
  }
}

// ---------------------------------------------------------------------------
// W2[v][i*256+j] = w[v][tri(min,max)] * (i==j ? 1 : 0.5)
__global__ __launch_bounds__(256) void build_w2(const float* __restrict__ w_type,
                                                const float* __restrict__ w_flag,
                                                float* __restrict__ W2)
{
  const int v = blockIdx.x >> 6, chunk = blockIdx.x & 63;
  const float* src = (v < 4) ? (w_type + (size_t)v * 32896) : w_flag;
  const int e0 = chunk * 1024 + threadIdx.x * 4;
#pragma unroll
  for (int q = 0; q < 4; ++q) {
    const int e = e0 + q;
    const int i = e >> 8, j = e & 255;
    const int r = i < j ? i : j, c = i < j ? j : i;
    const int t = r * 256 - (r * (r - 1)) / 2 + (c - r);
    W2[(size_t)v * 65536 + e] = src[t] * (i == j ? 1.0f : 0.5f);
  }
}

// ---------------------------------------------------------------------------
// Per-row mean + trace(cov), from X in fmt.
__global__ __launch_bounds__(256) void meanvar(const char* __restrict__ X,
                                               float* __restrict__ mu,
                                               float* __restrict__ nrm)
{
  const int b = blockIdx.x, i = threadIdx.x;
  const char* rp0 = X + (size_t)b * 262144 + (size_t)i * 128;
  float s = 0.f, ss = 0.f;
  for (int kt = 0; kt < 8; ++kt) {
    const char* rp = rp0 + kt * 32768;
#pragma unroll
    for (int sl = 0; sl < 4; ++sl) {
      bf16x8 h8 = *(const bf16x8*)(rp + ((sl ^ (i & 7)) << 4));
      bf16x8 l8 = *(const bf16x8*)(rp + (((sl + 4) ^ (i & 7)) << 4));
#pragma unroll
      for (int e = 0; e < 8; ++e) {
        const float v = bf16v(h8[e]) + bf16v(l8[e]);
        s += v; ss += v * v;
      }
    }
  }
  const float m = s * (1.f / 256.f);
  mu[b * 256 + i] = m;
  __shared__ float red[256];
  red[i] = ss * (1.f / 256.f) - m * m;
  __syncthreads();
  for (int o = 128; o > 0; o >>= 1) {
    if (i < o) red[i] += red[i + o];
    __syncthreads();
  }
  if (i == 0) nrm[b] = red[0];
}

// ---------------------------------------------------------------------------
// Heads: out[b,v] = dot(S_b, W2_v) + bias. Coalesced float4.
__global__ __launch_bounds__(256) void head2(
    const float* __restrict__ Sf, const float* __restrict__ W2,
    const float* __restrict__ b_type, const float* __restrict__ b_flag,
    float* __restrict__ out)
{
  const int b = blockIdx.x, v = blockIdx.y, tid = threadIdx.x;
  const float4* s4 = (const float4*)(Sf + (size_t)b * 65536);
  const float4* w4 = (const float4*)(W2 + (size_t)v * 65536);
  float acc = 0.f;
  for (int i = tid; i < 16384; i += 256) {
    const float4 a = s4[i], c = w4[i];
    acc += a.x * c.x + a.y * c.y + a.z * c.z + a.w * c.w;
  }
  __shared__ float red[256];
  red[tid] = acc;
  __syncthreads();
  for (int o = 128; o > 0; o >>= 1) {
    if (tid < o) red[tid] += red[tid + o];
    __syncthreads();
  }
  if (tid == 0) {
    if (v < 4) out[b * 4 + v] = red[0] + b_type[v];
    else       out[256 + b] = red[0] + b_flag[0];
  }
}

// ---------------------------------------------------------------------------
extern "C" void kernel_launch(void* const* d_in, const int* in_sizes, int n_in,
                              void* d_out, int out_size, void* d_ws, size_t ws_size,
                              hipStream_t stream)
{
  const float* features = (const float*)d_in[0];
  const float* w_bn     = (const float*)d_in[1];
  const float* b_bn     = (const float*)d_in[2];
  const float* w_type   = (const float*)d_in[3];
  const float* b_type   = (const float*)d_in[4];
  const float* w_flag   = (const float*)d_in[5];
  const float* b_flag   = (const float*)d_in[6];
  float* out = (float*)d_out;

  char* W = (char*)d_ws;
  const size_t PB = 16777216;
  char* P0 = W;           char* P1 = W + PB;     char* P2 = W + 2 * PB;
  char* P3 = W + 3 * PB;  char* P4 = W + 4 * PB;
  char* Wf = W + 5 * PB;            // 2 MB; dead after conv -> W2 aliases it
  float* W2 = (float*)Wf;           // 1.31 MB
  float* mu = (float*)(W + 5 * PB + 2097152);
  float* nrm = mu + 64 * 256;
  float* Sf = (float*)P4;           // final S fp32 (P4 dead by then)

  const dim3 tgrid(10, 1, 64), tgrid2(10, 1, 128), tb(128);

  cvt_w<<<dim3(64), dim3(256), 0, stream>>>(w_bn, Wf);
  conv_k<<<dim3(4, 2, 64), dim3(256), 0, stream>>>(Wf, features, P0, b_bn);
  build_w2<<<dim3(320), dim3(256), 0, stream>>>(w_type, w_flag, W2);
  meanvar<<<dim3(64), dim3(256), 0, stream>>>(P0, mu, nrm);

  // cov -> An (P1), Z0 (P2)
  gemm_s<E_COV, false><<<tgrid, tb, 0, stream>>>(
      P0, P0, P1, nullptr, nullptr, nullptr, P2, mu, nrm, nullptr);
  // Y0 = An @ Z0 -> P3
  gemm_s<E_T, false><<<tgrid, tb, 0, stream>>>(
      P1, P2, P3, nullptr, nullptr, nullptr, nullptr, nullptr, nullptr, nullptr);
  // it0: ZY=0.5(3I-Z@Y): Z=P2,Y=P3 -> P4 ; Yn=P3@P4->P0, Zn=P4@P2->P1
  gemm_s<E_TNS, false><<<tgrid, tb, 0, stream>>>(
      P2, P3, P4, nullptr, nullptr, nullptr, nullptr, nullptr, nullptr, nullptr);
  gemm_s<E_T, true><<<tgrid2, tb, 0, stream>>>(
      P3, P4, P0, P4, P2, P1, nullptr, nullptr, nullptr, nullptr);
  // it1: Z=P1,Y=P0 -> ZY=P2 ; Yn=P0@P2->P3, Zn=P2@P1->P4
  gemm_s<E_TNS, false><<<tgrid, tb, 0, stream>>>(
      P1, P0, P2, nullptr, nullptr, nullptr, nullptr, nullptr, nullptr, nullptr);
  gemm_s<E_T, true><<<tgrid2, tb, 0, stream>>>(
      P0, P2, P3, P2, P1, P4, nullptr, nullptr, nullptr, nullptr);
  // it2: Z=P4,Y=P3 -> ZY=P0 ; Yn=P3@P0->P1, Zn=P0@P4->P2
  gemm_s<E_TNS, false><<<tgrid, tb, 0, stream>>>(
      P4, P3, P0, nullptr, nullptr, nullptr, nullptr, nullptr, nullptr, nullptr);
  gemm_s<E_T, true><<<tgrid2, tb, 0, stream>>>(
      P3, P0, P1, P0, P4, P2, nullptr, nullptr, nullptr, nullptr);
  // final: E = 0.5(3I - Z@Y): Z=P2,Y=P1 -> P3 ; S = (Y@E)*sqrt(nrm) -> Sf
  gemm_s<E_TNS, false><<<tgrid, tb, 0, stream>>>(
      P2, P1, P3, nullptr, nullptr, nullptr, nullptr, nullptr, nullptr, nullptr);
  gemm_s<E_SF32, false><<<tgrid, tb, 0, stream>>>(
      P1, P3, nullptr, nullptr, nullptr, nullptr, nullptr, nullptr, nrm, Sf);

  head2<<<dim3(64, 5), dim3(256), 0, stream>>>(Sf, W2, b_type, b_flag, out);
  (void)in_sizes; (void)n_in; (void)out_size; (void)ws_size;
}

// Round 5
// 280.224 us; speedup vs baseline: 2.9808x; 1.1976x over previous
//
#include <hip/hip_runtime.h>
#include <math.h>

// ---------------------------------------------------------------------------
// HPFNetCovPool round 5.
// fmt storage (unchanged): [batch][kt=k/32][row(256)][128B]; 128B = 8x16B
// slots, slot_log = plane*4 + ((k&31)>>3), stored at slot_log ^ (row&7).
// Every MFMA fragment (row, 8-k-run, plane) is a contiguous 16B chunk ->
// kernels read fragments DIRECTLY from global (L1/L2 cached), no staging LDS,
// no barriers. 2-deep register prefetch covers latency.
// NS chain: column-fused kernels: P = Z@Y[:,c] (LDS), then
// Yn = 1.5Y - 0.5 Y@P, Zn = 1.5Z - 0.5 Z@P. One dispatch per NS iteration.
// ---------------------------------------------------------------------------

typedef __attribute__((ext_vector_type(8))) short bf16x8;
typedef __attribute__((ext_vector_type(4))) float f32x4;
typedef __attribute__((ext_vector_type(4))) unsigned u32x4;
typedef __attribute__((ext_vector_type(2))) unsigned u32x2;

__device__ __forceinline__ unsigned fbits(float f) { union { float f; unsigned u; } x; x.f = f; return x.u; }
__device__ __forceinline__ float bitsf(unsigned u) { union { float f; unsigned u; } x; x.u = u; return x.f; }
__device__ __forceinline__ float bf16v(short h) { return bitsf(((unsigned)(unsigned short)h) << 16); }

__device__ __forceinline__ unsigned pack_h(float a, float b) {
  return (fbits(a) >> 16) | (fbits(b) & 0xFFFF0000u);
}
__device__ __forceinline__ unsigned pack_l(float a, float b) {
  float la = a - bitsf(fbits(a) & 0xFFFF0000u);
  float lb = b - bitsf(fbits(b) & 0xFFFF0000u);
  return (fbits(la) >> 16) | (fbits(lb) & 0xFFFF0000u);
}

// fragment pointer into global fmt
__device__ __forceinline__ const bf16x8* fragp(const char* M, int kt, int row,
                                               int g, int pl) {
  return (const bf16x8*)(M + (size_t)kt * 32768 + (size_t)row * 128 +
                         ((((pl << 2) + g) ^ (row & 7)) << 4));
}
// fragment pointer into LDS P-panel (kt-stride 8 KB: 64 rows x 128B)
__device__ __forceinline__ const bf16x8* fragl(const char* L, int kt, int row,
                                               int g, int pl) {
  return (const bf16x8*)(L + kt * 8192 + row * 128 +
                         ((((pl << 2) + g) ^ (row & 7)) << 4));
}

__device__ __forceinline__ void write_quad_g(char* M, int row, int k0,
                                             const float* v) {
  char* rp = M + (size_t)(k0 >> 5) * 32768 + (size_t)row * 128;
  const int s = (k0 & 31) >> 3, bo = (k0 & 7) * 2;
  *(u32x2*)(rp + (((s) ^ (row & 7)) << 4) + bo) =
      (u32x2){pack_h(v[0], v[1]), pack_h(v[2], v[3])};
  *(u32x2*)(rp + (((s + 4) ^ (row & 7)) << 4) + bo) =
      (u32x2){pack_l(v[0], v[1]), pack_l(v[2], v[3])};
}
__device__ __forceinline__ void write_quad_l(char* L, int row, int k0,
                                             const float* v) {
  char* rp = L + (k0 >> 5) * 8192 + row * 128;
  const int s = (k0 & 31) >> 3, bo = (k0 & 7) * 2;
  *(u32x2*)(rp + (((s) ^ (row & 7)) << 4) + bo) =
      (u32x2){pack_h(v[0], v[1]), pack_h(v[2], v[3])};
  *(u32x2*)(rp + (((s + 4) ^ (row & 7)) << 4) + bo) =
      (u32x2){pack_l(v[0], v[1]), pack_l(v[2], v[3])};
}
__device__ __forceinline__ void read_quad_g(const char* M, int row, int k0,
                                            float* v) {
  const char* rp = M + (size_t)(k0 >> 5) * 32768 + (size_t)row * 128;
  const int s = (k0 & 31) >> 3, bo = (k0 & 7) * 2;
  const u32x2 hq = *(const u32x2*)(rp + (((s) ^ (row & 7)) << 4) + bo);
  const u32x2 lq = *(const u32x2*)(rp + (((s + 4) ^ (row & 7)) << 4) + bo);
  v[0] = bitsf(hq[0] << 16) + bitsf(lq[0] << 16);
  v[1] = bitsf(hq[0] & 0xFFFF0000u) + bitsf(lq[0] & 0xFFFF0000u);
  v[2] = bitsf(hq[1] << 16) + bitsf(lq[1] << 16);
  v[3] = bitsf(hq[1] & 0xFFFF0000u) + bitsf(lq[1] & 0xFFFF0000u);
}

#define MFMA3(c, aH, aL, bH, bL)                                            \
  c = __builtin_amdgcn_mfma_f32_16x16x32_bf16(aL, bH, c, 0, 0, 0);          \
  c = __builtin_amdgcn_mfma_f32_16x16x32_bf16(aH, bL, c, 0, 0, 0);          \
  c = __builtin_amdgcn_mfma_f32_16x16x32_bf16(aH, bH, c, 0, 0, 0);

// ---------------------------------------------------------------------------
// conv: X[b](256ch x 256px) = w_bn(fmt) @ F[b] + bias -> X fmt.
// grid (4 jb, 2 ib, 64 bz), 256 thr, 4 waves (2x2). No LDS, no barriers.
__global__ __launch_bounds__(256) void conv_k(
    const char* __restrict__ Wf, const float* __restrict__ F,
    char* __restrict__ X, const float* __restrict__ bias)
{
  const int tid = threadIdx.x, lane = tid & 63, w = tid >> 6;
  const int wr = w >> 1, wc = w & 1, fr = lane & 15, g = lane >> 4;
  const int bz = blockIdx.z, ib = blockIdx.y * 128, jb = blockIdx.x * 64;
  const float* Fb = F + (size_t)bz * 524288;

  f32x4 acc[4][2] = {};
  bf16x8 pa[2][4][2];
  float xv[2][16];

#pragma unroll
  for (int par = 0; par < 2; ++par) {
#pragma unroll
    for (int m = 0; m < 4; ++m) {
      const int r = ib + wr * 64 + m * 16 + fr;
#pragma unroll
      for (int pl = 0; pl < 2; ++pl) pa[par][m][pl] = *fragp(Wf, par, r, g, pl);
    }
    const float* src = Fb + ((size_t)par * 32 + g * 8) * 256 + jb + wc * 32 + fr;
#pragma unroll
    for (int n = 0; n < 2; ++n)
#pragma unroll
      for (int e = 0; e < 8; ++e) xv[par][n * 8 + e] = src[e * 256 + n * 16];
  }

  for (int t2 = 0; t2 < 64; t2 += 2) {
#pragma unroll
    for (int par = 0; par < 2; ++par) {
      const int t = t2 + par;
      bf16x8 aH[4], aL[4];
#pragma unroll
      for (int m = 0; m < 4; ++m) { aH[m] = pa[par][m][0]; aL[m] = pa[par][m][1]; }
      bf16x8 bH[2], bL[2];
#pragma unroll
      for (int n = 0; n < 2; ++n) {
        short hh[8], ll[8];
#pragma unroll
        for (int e = 0; e < 8; ++e) {
          const float v = xv[par][n * 8 + e];
          const unsigned u = fbits(v);
          hh[e] = (short)(u >> 16);
          ll[e] = (short)(fbits(v - bitsf(u & 0xFFFF0000u)) >> 16);
        }
        bH[n] = *(bf16x8*)hh; bL[n] = *(bf16x8*)ll;
      }
      if (t + 2 < 64) {
#pragma unroll
        for (int m = 0; m < 4; ++m) {
          const int r = ib + wr * 64 + m * 16 + fr;
#pragma unroll
          for (int pl = 0; pl < 2; ++pl)
            pa[par][m][pl] = *fragp(Wf, t + 2, r, g, pl);
        }
        const float* src =
            Fb + ((size_t)(t + 2) * 32 + g * 8) * 256 + jb + wc * 32 + fr;
#pragma unroll
        for (int n = 0; n < 2; ++n)
#pragma unroll
          for (int e = 0; e < 8; ++e)
            xv[par][n * 8 + e] = src[e * 256 + n * 16];
      }
#pragma unroll
      for (int m = 0; m < 4; ++m)
#pragma unroll
        for (int n = 0; n < 2; ++n) {
          f32x4 c = acc[m][n];
          MFMA3(c, aH[m], aL[m], bH[n], bL[n]);
          acc[m][n] = c;
        }
    }
  }

  // epilogue: X fmt row = channel gi, k = pixel gj
  char* Xb = X + (size_t)bz * 262144;
#pragma unroll
  for (int m = 0; m < 4; ++m) {
    const int gi0 = ib + wr * 64 + m * 16 + g * 4;
#pragma unroll
    for (int n = 0; n < 2; ++n) {
      const int gj = jb + wc * 32 + n * 16 + fr;
      const int ktj = gj >> 5, sj = (gj & 31) >> 3, bo = (gj & 7) * 2;
#pragma unroll
      for (int j = 0; j < 4; ++j) {
        const int gi = gi0 + j;
        char* rp = Xb + (size_t)ktj * 32768 + (size_t)gi * 128;
        const float v = acc[m][n][j] + bias[gi];
        const unsigned u = fbits(v);
        *(short*)(rp + ((sj ^ (gi & 7)) << 4) + bo) = (short)(u >> 16);
        *(short*)(rp + (((sj + 4) ^ (gi & 7)) << 4) + bo) =
            (short)(fbits(v - bitsf(u & 0xFFFF0000u)) >> 16);
      }
    }
  }
}

// ---------------------------------------------------------------------------
// Column-fused NS kernel. grid 256 x 512 thr (8 waves, rows 32/wave).
// MODE 0 COV : s1 out = X@X^T col-panel -> An(outA), Z0(outB)
// MODE 1 Y0  : s1 out = An@An col-panel -> Y0 = 1.5An - 0.5 An^2 (outA)
// MODE 2 IT  : s1 P = Z@Y[:,c] -> LDS; s2 Yn(outA), Zn(outB)
// MODE 3 FIN : s1 P -> LDS; s2 S = (1.5Y - 0.5 Y@P) * sqrt(nrm) -> Sf (fp32)
template <int MODE>
__global__ __launch_bounds__(512) void col_k(
    const char* __restrict__ A1, const char* __restrict__ Bsrc,
    const char* __restrict__ Ys, const char* __restrict__ Zs,
    char* __restrict__ outA, char* __restrict__ outB,
    const float* __restrict__ mu, const float* __restrict__ nrm,
    float* __restrict__ Sf)
{
  __shared__ __align__(16) char Plds[65536];
  const int tid = threadIdx.x, lane = tid & 63, w = tid >> 6;
  const int fr = lane & 15, g = lane >> 4;
  const int blk = blockIdx.x;
  const int bz = (blk & 7) * 8 + ((blk >> 3) & 7);  // XCD batch affinity
  const int jb = (blk >> 6) * 64;
  const size_t MB = 262144;
  const char* Ab = A1 + (size_t)bz * MB;
  const char* Bb = Bsrc + (size_t)bz * MB;
  const int r0 = g * 4;

  // ---------------- stage 1: acc(256x64 over waves) = A @ Bcol^T -----------
  f32x4 acc[2][4] = {};
  {
    bf16x8 pa[2][2][2], pb[2][4][2];
#pragma unroll
    for (int par = 0; par < 2; ++par) {
#pragma unroll
      for (int m = 0; m < 2; ++m) {
        const int r = w * 32 + m * 16 + fr;
#pragma unroll
        for (int pl = 0; pl < 2; ++pl) pa[par][m][pl] = *fragp(Ab, par, r, g, pl);
      }
#pragma unroll
      for (int n = 0; n < 4; ++n) {
        const int r = jb + n * 16 + fr;
#pragma unroll
        for (int pl = 0; pl < 2; ++pl) pb[par][n][pl] = *fragp(Bb, par, r, g, pl);
      }
    }
    for (int t2 = 0; t2 < 8; t2 += 2) {
#pragma unroll
      for (int par = 0; par < 2; ++par) {
        const int t = t2 + par;
        bf16x8 aH[2], aL[2], bH[4], bL[4];
#pragma unroll
        for (int m = 0; m < 2; ++m) { aH[m] = pa[par][m][0]; aL[m] = pa[par][m][1]; }
#pragma unroll
        for (int n = 0; n < 4; ++n) { bH[n] = pb[par][n][0]; bL[n] = pb[par][n][1]; }
        if (t + 2 < 8) {
#pragma unroll
          for (int m = 0; m < 2; ++m) {
            const int r = w * 32 + m * 16 + fr;
#pragma unroll
            for (int pl = 0; pl < 2; ++pl)
              pa[par][m][pl] = *fragp(Ab, t + 2, r, g, pl);
          }
#pragma unroll
          for (int n = 0; n < 4; ++n) {
            const int r = jb + n * 16 + fr;
#pragma unroll
            for (int pl = 0; pl < 2; ++pl)
              pb[par][n][pl] = *fragp(Bb, t + 2, r, g, pl);
          }
        }
#pragma unroll
        for (int m = 0; m < 2; ++m)
#pragma unroll
          for (int n = 0; n < 4; ++n) {
            f32x4 c = acc[m][n];
            MFMA3(c, aH[m], aL[m], bH[n], bL[n]);
            acc[m][n] = c;
          }
      }
    }
  }

  if constexpr (MODE == 0) {  // COV -> An + Z0
    const float rn = 1.0f / nrm[bz];
    const float* mub = mu + bz * 256;
    char* oA = outA + (size_t)bz * MB;
    char* oB = outB + (size_t)bz * MB;
#pragma unroll
    for (int m = 0; m < 2; ++m) {
      const int gi0 = w * 32 + m * 16 + r0;
#pragma unroll
      for (int n = 0; n < 4; ++n) {
        const int gj = jb + n * 16 + fr;
        float vv[4], zz[4];
#pragma unroll
        for (int j = 0; j < 4; ++j) {
          const float v =
              (acc[m][n][j] * (1.f / 256.f) - mub[gi0 + j] * mub[gj]) * rn;
          vv[j] = v;
          zz[j] = (gi0 + j == gj ? 1.5f : 0.f) - 0.5f * v;
        }
        write_quad_g(oA, gj, gi0, vv);
        write_quad_g(oB, gj, gi0, zz);
      }
    }
  } else if constexpr (MODE == 1) {  // Y0 = 1.5An - 0.5 An^2
    char* oA = outA + (size_t)bz * MB;
#pragma unroll
    for (int m = 0; m < 2; ++m) {
      const int gi0 = w * 32 + m * 16 + r0;
#pragma unroll
      for (int n = 0; n < 4; ++n) {
        const int gj = jb + n * 16 + fr;
        float av[4], vv[4];
        read_quad_g(Bb, gj, gi0, av);
#pragma unroll
        for (int j = 0; j < 4; ++j) vv[j] = 1.5f * av[j] - 0.5f * acc[m][n][j];
        write_quad_g(oA, gj, gi0, vv);
      }
    }
  } else {  // IT / FIN
    // pack P^T panel into LDS fmt
#pragma unroll
    for (int m = 0; m < 2; ++m) {
      const int gi0 = w * 32 + m * 16 + r0;
#pragma unroll
      for (int n = 0; n < 4; ++n) {
        const int jl = n * 16 + fr;
        float vv[4] = {acc[m][n][0], acc[m][n][1], acc[m][n][2], acc[m][n][3]};
        write_quad_l(Plds, jl, gi0, vv);
      }
    }
    __syncthreads();

    const char* Yb = Ys + (size_t)bz * MB;
    const char* Zb = (MODE == 2) ? (Zs + (size_t)bz * MB) : nullptr;
    f32x4 aY[2][4] = {}, aZ[2][4] = {};
    bf16x8 py[2][2][2], pz[2][2][2];
#pragma unroll
    for (int par = 0; par < 2; ++par)
#pragma unroll
      for (int m = 0; m < 2; ++m) {
        const int r = w * 32 + m * 16 + fr;
#pragma unroll
        for (int pl = 0; pl < 2; ++pl) {
          py[par][m][pl] = *fragp(Yb, par, r, g, pl);
          if constexpr (MODE == 2) pz[par][m][pl] = *fragp(Zb, par, r, g, pl);
        }
      }
    for (int t2 = 0; t2 < 8; t2 += 2) {
#pragma unroll
      for (int par = 0; par < 2; ++par) {
        const int t = t2 + par;
        bf16x8 yH[2], yL[2], zH[2], zL[2];
#pragma unroll
        for (int m = 0; m < 2; ++m) {
          yH[m] = py[par][m][0]; yL[m] = py[par][m][1];
          if constexpr (MODE == 2) { zH[m] = pz[par][m][0]; zL[m] = pz[par][m][1]; }
        }
        if (t + 2 < 8) {
#pragma unroll
          for (int m = 0; m < 2; ++m) {
            const int r = w * 32 + m * 16 + fr;
#pragma unroll
            for (int pl = 0; pl < 2; ++pl) {
              py[par][m][pl] = *fragp(Yb, t + 2, r, g, pl);
              if constexpr (MODE == 2) pz[par][m][pl] = *fragp(Zb, t + 2, r, g, pl);
            }
          }
        }
        bf16x8 bH[4], bL[4];
#pragma unroll
        for (int n = 0; n < 4; ++n) {
          const int jl = n * 16 + fr;
          bH[n] = *fragl(Plds, t, jl, g, 0);
          bL[n] = *fragl(Plds, t, jl, g, 1);
        }
#pragma unroll
        for (int m = 0; m < 2; ++m)
#pragma unroll
          for (int n = 0; n < 4; ++n) {
            f32x4 cy = aY[m][n];
            MFMA3(cy, yH[m], yL[m], bH[n], bL[n]);
            aY[m][n] = cy;
            if constexpr (MODE == 2) {
              f32x4 cz = aZ[m][n];
              MFMA3(cz, zH[m], zL[m], bH[n], bL[n]);
              aZ[m][n] = cz;
            }
          }
      }
    }
    // epilogue
    if constexpr (MODE == 2) {
      char* oA = outA + (size_t)bz * MB;
      char* oB = outB + (size_t)bz * MB;
#pragma unroll
      for (int m = 0; m < 2; ++m) {
        const int gi0 = w * 32 + m * 16 + r0;
#pragma unroll
        for (int n = 0; n < 4; ++n) {
          const int gj = jb + n * 16 + fr;
          float base[4], vv[4];
          read_quad_g(Yb, gj, gi0, base);
#pragma unroll
          for (int j = 0; j < 4; ++j) vv[j] = 1.5f * base[j] - 0.5f * aY[m][n][j];
          write_quad_g(oA, gj, gi0, vv);
          read_quad_g(Zb, gj, gi0, base);
#pragma unroll
          for (int j = 0; j < 4; ++j) vv[j] = 1.5f * base[j] - 0.5f * aZ[m][n][j];
          write_quad_g(oB, gj, gi0, vv);
        }
      }
    } else {  // FIN
      const float sq = sqrtf(nrm[bz]);
      float* Sb = Sf + (size_t)bz * 65536;
#pragma unroll
      for (int m = 0; m < 2; ++m) {
        const int gi0 = w * 32 + m * 16 + r0;
#pragma unroll
        for (int n = 0; n < 4; ++n) {
          const int gj = jb + n * 16 + fr;
          float base[4];
          read_quad_g(Yb, gj, gi0, base);
          f32x4 vv;
#pragma unroll
          for (int j = 0; j < 4; ++j)
            vv[j] = (1.5f * base[j] - 0.5f * aY[m][n][j]) * sq;
          *(f32x4*)(Sb + (size_t)gj * 256 + gi0) = vv;
        }
      }
    }
  }
}

// ---------------------------------------------------------------------------
// w_bn [256][2048] fp32 -> fmt.
__global__ __launch_bounds__(256) void cvt_w(const float* __restrict__ wsrc,
                                             char* __restrict__ Wf)
{
  const int kt = blockIdx.x, r = threadIdx.x;
  const float* src = wsrc + (size_t)r * 2048 + kt * 32;
  char* rp = Wf + (size_t)kt * 32768 + (size_t)r * 128;
#pragma unroll
  for (int s = 0; s < 4; ++s) {
    float x[8];
#pragma unroll
    for (int e = 0; e < 8; ++e) x[e] = src[s * 8 + e];
    *(u32x4*)(rp + ((s ^ (r & 7)) << 4)) =
        (u32x4){pack_h(x[0], x[1]), pack_h(x[2], x[3]), pack_h(x[4], x[5]), pack_h(x[6], x[7])};
    *(u32x4*)(rp + (((s + 4) ^ (r & 7)) << 4)) =
        (u32x4){pack_l(x[0], x[1]), pack_l(x[2], x[3]), pack_l(x[4], x[5]), pack_l(x[6], x[7])};
  }
}

// ---------------------------------------------------------------------------
// W2[v][i*256+j] = w[v][tri(min,max)] * (i==j ? 1 : 0.5)
__global__ __launch_bounds__(256) void build_w2(const float* __restrict__ w_type,
                                                const float* __restrict__ w_flag,
                                                float* __restrict__ W2)
{
  const int v = blockIdx.x >> 6, chunk = blockIdx.x & 63;
  const float* src = (v < 4) ? (w_type + (size_t)v * 32896) : w_flag;
  const int e0 = chunk * 1024 + threadIdx.x * 4;
#pragma unroll
  for (int q = 0; q < 4; ++q) {
    const int e = e0 + q;
    const int i = e >> 8, j = e & 255;
    const int r = i < j ? i : j, c = i < j ? j : i;
    const int t = r * 256 - (r * (r - 1)) / 2 + (c - r);
    W2[(size_t)v * 65536 + e] = src[t] * (i == j ? 1.0f : 0.5f);
  }
}

// ---------------------------------------------------------------------------
// Per-row mean + trace(cov), from X in fmt.
__global__ __launch_bounds__(256) void meanvar(const char* __restrict__ X,
                                               float* __restrict__ mu,
                                               float* __restrict__ nrm)
{
  const int b = blockIdx.x, i = threadIdx.x;
  const char* rp0 = X + (size_t)b * 262144 + (size_t)i * 128;
  float s = 0.f, ss = 0.f;
  for (int kt = 0; kt < 8; ++kt) {
    const char* rp = rp0 + kt * 32768;
#pragma unroll
    for (int sl = 0; sl < 4; ++sl) {
      bf16x8 h8 = *(const bf16x8*)(rp + ((sl ^ (i & 7)) << 4));
      bf16x8 l8 = *(const bf16x8*)(rp + (((sl + 4) ^ (i & 7)) << 4));
#pragma unroll
      for (int e = 0; e < 8; ++e) {
        const float v = bf16v(h8[e]) + bf16v(l8[e]);
        s += v; ss += v * v;
      }
    }
  }
  const float m = s * (1.f / 256.f);
  mu[b * 256 + i] = m;
  __shared__ float red[256];
  red[i] = ss * (1.f / 256.f) - m * m;
  __syncthreads();
  for (int o = 128; o > 0; o >>= 1) {
    if (i < o) red[i] += red[i + o];
    __syncthreads();
  }
  if (i == 0) nrm[b] = red[0];
}

// ---------------------------------------------------------------------------
// Heads: out[b,v] = dot(S_b, W2_v) + bias.
__global__ __launch_bounds__(256) void head2(
    const float* __restrict__ Sf, const float* __restrict__ W2,
    const float* __restrict__ b_type, const float* __restrict__ b_flag,
    float* __restrict__ out)
{
  const int b = blockIdx.x, v = blockIdx.y, tid = threadIdx.x;
  const float4* s4 = (const float4*)(Sf + (size_t)b * 65536);
  const float4* w4 = (const float4*)(W2 + (size_t)v * 65536);
  float acc = 0.f;
  for (int i = tid; i < 16384; i += 256) {
    const float4 a = s4[i], c = w4[i];
    acc += a.x * c.x + a.y * c.y + a.z * c.z + a.w * c.w;
  }
  __shared__ float red[256];
  red[tid] = acc;
  __syncthreads();
  for (int o = 128; o > 0; o >>= 1) {
    if (tid < o) red[tid] += red[tid + o];
    __syncthreads();
  }
  if (tid == 0) {
    if (v < 4) out[b * 4 + v] = red[0] + b_type[v];
    else       out[256 + b] = red[0] + b_flag[0];
  }
}

// ---------------------------------------------------------------------------
extern "C" void kernel_launch(void* const* d_in, const int* in_sizes, int n_in,
                              void* d_out, int out_size, void* d_ws, size_t ws_size,
                              hipStream_t stream)
{
  const float* features = (const float*)d_in[0];
  const float* w_bn     = (const float*)d_in[1];
  const float* b_bn     = (const float*)d_in[2];
  const float* w_type   = (const float*)d_in[3];
  const float* b_type   = (const float*)d_in[4];
  const float* w_flag   = (const float*)d_in[5];
  const float* b_flag   = (const float*)d_in[6];
  float* out = (float*)d_out;

  char* W = (char*)d_ws;
  const size_t PB = 16777216;
  char* P0 = W;           char* P1 = W + PB;     char* P2 = W + 2 * PB;
  char* P3 = W + 3 * PB;  char* P4 = W + 4 * PB;
  char* Wf = W + 5 * PB;            // 2 MB; dead after conv -> W2 aliases it
  float* W2 = (float*)Wf;
  float* mu = (float*)(W + 5 * PB + 2097152);
  float* nrm = mu + 64 * 256;
  float* Sf = (float*)P4;           // final S fp32 (P4 dead by then)

  cvt_w<<<dim3(64), dim3(256), 0, stream>>>(w_bn, Wf);
  conv_k<<<dim3(4, 2, 64), dim3(256), 0, stream>>>(Wf, features, P0, b_bn);
  build_w2<<<dim3(320), dim3(256), 0, stream>>>(w_type, w_flag, W2);
  meanvar<<<dim3(64), dim3(256), 0, stream>>>(P0, mu, nrm);

  const dim3 cg(256), cb(512);
  // cov: An(P1), Z0(P2)
  col_k<0><<<cg, cb, 0, stream>>>(P0, P0, nullptr, nullptr, P1, P2, mu, nrm, nullptr);
  // Y0(P3) = 1.5An - 0.5 An^2
  col_k<1><<<cg, cb, 0, stream>>>(P1, P1, nullptr, nullptr, P3, nullptr, nullptr, nullptr, nullptr);
  // it1: Z=P2, Y=P3 -> Yn P0, Zn P4
  col_k<2><<<cg, cb, 0, stream>>>(P2, P3, P3, P2, P0, P4, nullptr, nullptr, nullptr);
  // it2: Z=P4, Y=P0 -> Yn P1, Zn P2
  col_k<2><<<cg, cb, 0, stream>>>(P4, P0, P0, P4, P1, P2, nullptr, nullptr, nullptr);
  // it3: Z=P2, Y=P1 -> Yn P3, Zn P0
  col_k<2><<<cg, cb, 0, stream>>>(P2, P1, P1, P2, P3, P0, nullptr, nullptr, nullptr);
  // fin: Z=P0, Y=P3 -> Sf
  col_k<3><<<cg, cb, 0, stream>>>(P0, P3, P3, nullptr, nullptr, nullptr, nullptr, nrm, Sf);

  head2<<<dim3(64, 5), dim3(256), 0, stream>>>(Sf, W2, b_type, b_flag, out);
  (void)in_sizes; (void)n_in; (void)out_size; (void)ws_size;
}